// Round 15
// baseline (90.989 us; speedup 1.0000x reference)
//
#include <hip/hip_runtime.h>
#include <math.h>

#define B_ 2
#define L_ 2048
#define D_ 256
#define P_ 32
#define NC_ 64
#define CL_ 32

#define INV_SQRT_P 0.17677669529663687f   // 1/sqrt(32)
#define PI_F 3.14159265358979323846f

typedef __attribute__((ext_vector_type(8))) short bf16x8;
typedef __attribute__((ext_vector_type(4))) float f32x4;

__device__ __forceinline__ float gelu_exact(float x){
    return 0.5f * x * (1.0f + erff(x * 0.70710678118654752f));
}

__device__ __forceinline__ unsigned short f2bf(float f){
    unsigned int u = __float_as_uint(f);
    u += 0x7FFFu + ((u >> 16) & 1u);     // round-to-nearest-even
    return (unsigned short)(u >> 16);
}

__device__ __forceinline__ float bf2f(unsigned short u){
    return __uint_as_float(((unsigned int)u) << 16);
}

// ---------------- K_prep: weight bf16 repacks + pos sincos ----------
__global__ __launch_bounds__(256) void k_prep(
    const float* __restrict__ pos_phases,
    const float* __restrict__ w_pv, const float* __restrict__ w_kv,
    const float* __restrict__ w_vg1, const float* __restrict__ w_bg1,
    const float* __restrict__ w_r1, const float* __restrict__ w_r2,
    const float* __restrict__ w_out, const float* __restrict__ w_key,
    unsigned short* __restrict__ wq,
    float* __restrict__ cpos, float* __restrict__ spos)
{
    int id = blockIdx.x * 256 + threadIdx.x;   // 0..696319
    if (id < 630784){
        const float* src; int N; int local;
        if (id < 65536)       { src = w_pv;  N = 256; local = id; }
        else if (id < 131072) { src = w_kv;  N = 256; local = id - 65536; }
        else if (id < 262144) { src = w_vg1; N = 256; local = id - 131072; }
        else if (id < 294912) { src = w_bg1; N = 128; local = id - 262144; }
        else if (id < 425984) { src = w_r1;  N = 512; local = id - 294912; }
        else if (id < 557056) { src = w_r2;  N = 256; local = id - 425984; }
        else if (id < 622592) { src = w_out; N = 256; local = id - 557056; }
        else                  { src = w_key; N = 32;  local = id - 622592; }
        int j = local & 7, lane = (local >> 3) & 63, tile = local >> 9;
        int NT = N >> 4;
        int nt = tile % NT, kt = tile / NT;
        int row = kt * 32 + ((lane >> 4) << 3) + j;
        int col = nt * 16 + (lane & 15);
        wq[id] = f2bf(src[(size_t)row * N + col]);
    } else {
        int idx = id - 630784;                 // 0..65535 = L*P
        float s, c;
        sincosf(pos_phases[idx], &s, &c);
        cpos[idx] = c;
        spos[idx] = s;
    }
}

// ---------------- K1: fused projections via MFMA, 16 tokens/block, 8 waves ----
// x tile (17 rows: shifted predecessor + 16 tokens) staged in LDS, coalesced.
__global__ __launch_bounds__(512) void k_proj(
    const float* __restrict__ x,
    const unsigned short* __restrict__ wq,
    const float* __restrict__ b_pv, const float* __restrict__ b_kv,
    const float* __restrict__ b_vg1,
    const float* __restrict__ w_vg2, const float* __restrict__ b_vg2,
    const float* __restrict__ b_bg1,
    const float* __restrict__ w_bg2, const float* __restrict__ b_bg2,
    const float* __restrict__ b_key,
    unsigned short* __restrict__ pvb, unsigned short* __restrict__ kvvb,
    float* __restrict__ ck, float* __restrict__ sk,
    float* __restrict__ vg, float* __restrict__ blend0, float* __restrict__ blend1)
{
    __shared__ float xt[17][260];       // [row 0 = token l0-1][col], pad stride 260
    __shared__ float hbuf[16][257];
    __shared__ float kvbuf[16][257];
    __shared__ float bhbuf[16][129];
    __shared__ float kph[16][33];
    __shared__ float red[16][17], red2[16][17], red3[16][17];
    __shared__ float vgs[16];

    const int i = threadIdx.x;
    const int lane = i & 63, w = i >> 6;
    const int b = blockIdx.x >> 7, lt = blockIdx.x & 127, l0 = lt * 16;
    const int g = lane >> 4, c = lane & 15;

    // ---- stage x tile into LDS (coalesced) ----
    for (int e = i; e < 17 * 256; e += 512){
        int row = e >> 8, col = e & 255;
        int tok = l0 - 1 + row;
        xt[row][col] = (tok >= 0) ? x[(size_t)(b * L_ + tok) * D_ + col] : 0.0f;
    }
    __syncthreads();

    // ---- pack A fragments from LDS ----
    bf16x8 xa[8], xs[8];
    {
        int rloc  = 1 + (lane & 15);            // current token row in xt
        int cbase = (lane >> 4) << 3;
        #pragma unroll
        for (int kt = 0; kt < 8; ++kt){
            float4 a0 = *(const float4*)&xt[rloc][kt * 32 + cbase];
            float4 a1 = *(const float4*)&xt[rloc][kt * 32 + cbase + 4];
            bf16x8 v;
            v[0] = (short)f2bf(a0.x); v[1] = (short)f2bf(a0.y);
            v[2] = (short)f2bf(a0.z); v[3] = (short)f2bf(a0.w);
            v[4] = (short)f2bf(a1.x); v[5] = (short)f2bf(a1.y);
            v[6] = (short)f2bf(a1.z); v[7] = (short)f2bf(a1.w);
            xa[kt] = v;
            float4 p0 = *(const float4*)&xt[rloc - 1][kt * 32 + cbase];
            float4 p1 = *(const float4*)&xt[rloc - 1][kt * 32 + cbase + 4];
            bf16x8 vp;
            vp[0] = (short)f2bf(p0.x); vp[1] = (short)f2bf(p0.y);
            vp[2] = (short)f2bf(p0.z); vp[3] = (short)f2bf(p0.w);
            vp[4] = (short)f2bf(p1.x); vp[5] = (short)f2bf(p1.y);
            vp[6] = (short)f2bf(p1.z); vp[7] = (short)f2bf(p1.w);
            xs[kt] = vp;
        }
    }

    const unsigned short* wpv  = wq;
    const unsigned short* wkv  = wq + 65536;
    const unsigned short* wvg1 = wq + 131072;
    const unsigned short* wbg1 = wq + 262144;
    const unsigned short* wkey = wq + 622592;

    // 58 tile jobs: [0,2) key, [2,18) pv, [18,34) kv, [34,50) vg1(K=512), [50,58) bg1
    for (int jb = w; jb < 58; jb += 8){
        f32x4 acc = {0.f, 0.f, 0.f, 0.f};
        if (jb < 2){
            int nt = jb;
            #pragma unroll
            for (int kt = 0; kt < 8; ++kt){
                bf16x8 bf = *(const bf16x8*)(wkey + (kt * 2 + nt) * 512 + lane * 8);
                acc = __builtin_amdgcn_mfma_f32_16x16x32_bf16(xa[kt], bf, acc, 0, 0, 0);
            }
            float bb = b_key[nt * 16 + c];
            #pragma unroll
            for (int r = 0; r < 4; ++r)
                kph[4 * g + r][nt * 16 + c] = acc[r] + bb;
        } else if (jb < 18){
            int nt = jb - 2;
            #pragma unroll
            for (int kt = 0; kt < 8; ++kt){
                bf16x8 bf = *(const bf16x8*)(wpv + (kt * 16 + nt) * 512 + lane * 8);
                acc = __builtin_amdgcn_mfma_f32_16x16x32_bf16(xa[kt], bf, acc, 0, 0, 0);
            }
            float bb = b_pv[nt * 16 + c];
            #pragma unroll
            for (int r = 0; r < 4; ++r)
                pvb[(size_t)(b * L_ + l0 + 4 * g + r) * D_ + nt * 16 + c] = f2bf(acc[r] + bb);
        } else if (jb < 34){
            int nt = jb - 18;
            #pragma unroll
            for (int kt = 0; kt < 8; ++kt){
                bf16x8 bf = *(const bf16x8*)(wkv + (kt * 16 + nt) * 512 + lane * 8);
                acc = __builtin_amdgcn_mfma_f32_16x16x32_bf16(xa[kt], bf, acc, 0, 0, 0);
            }
            float bb = b_kv[nt * 16 + c];
            #pragma unroll
            for (int r = 0; r < 4; ++r)
                kvbuf[4 * g + r][nt * 16 + c] = acc[r] + bb;
        } else if (jb < 50){
            int nt = jb - 34;
            #pragma unroll
            for (int kt = 0; kt < 8; ++kt){
                bf16x8 bf = *(const bf16x8*)(wvg1 + (kt * 16 + nt) * 512 + lane * 8);
                acc = __builtin_amdgcn_mfma_f32_16x16x32_bf16(xa[kt], bf, acc, 0, 0, 0);
            }
            #pragma unroll
            for (int kt = 8; kt < 16; ++kt){
                bf16x8 bf = *(const bf16x8*)(wvg1 + (kt * 16 + nt) * 512 + lane * 8);
                acc = __builtin_amdgcn_mfma_f32_16x16x32_bf16(xs[kt - 8], bf, acc, 0, 0, 0);
            }
            float bb = b_vg1[nt * 16 + c];
            #pragma unroll
            for (int r = 0; r < 4; ++r)
                hbuf[4 * g + r][nt * 16 + c] = gelu_exact(acc[r] + bb);
        } else {
            int nt = jb - 50;
            #pragma unroll
            for (int kt = 0; kt < 8; ++kt){
                bf16x8 bf = *(const bf16x8*)(wbg1 + (kt * 8 + nt) * 512 + lane * 8);
                acc = __builtin_amdgcn_mfma_f32_16x16x32_bf16(xa[kt], bf, acc, 0, 0, 0);
            }
            float bb = b_bg1[nt * 16 + c];
            #pragma unroll
            for (int r = 0; r < 4; ++r)
                bhbuf[4 * g + r][nt * 16 + c] = gelu_exact(acc[r] + bb);
        }
    }
    __syncthreads();

    // key phases -> phasors (fp32)
    {
        int t = i >> 5, p = i & 31;
        float a = tanhf(kph[t][p]) * PI_F;
        float s, cc;
        sincosf(a, &s, &cc);
        ck[(size_t)(b * L_ + l0 + t) * P_ + p] = cc;
        sk[(size_t)(b * L_ + l0 + t) * P_ + p] = s;
    }

    // vg2 (threads 0..255) and bg2 (threads 256..511) partial reductions
    if (i < 256){
        int t = i >> 4, c2 = i & 15;
        float s = 0.f;
        #pragma unroll
        for (int m = 0; m < 16; ++m){ int dd = c2 + 16 * m; s += hbuf[t][dd] * w_vg2[dd]; }
        red[t][c2] = s;
    } else {
        int ii = i - 256;
        int t = ii >> 4, c2 = ii & 15;
        float s0 = 0.f, s1 = 0.f;
        #pragma unroll
        for (int m = 0; m < 8; ++m){
            int jj = c2 + 16 * m;
            float v = bhbuf[t][jj];
            s0 += v * w_bg2[jj * 2 + 0];
            s1 += v * w_bg2[jj * 2 + 1];
        }
        red2[t][c2] = s0; red3[t][c2] = s1;
    }
    __syncthreads();
    if (i < 16){
        float s = 0.f;
        #pragma unroll
        for (int c2 = 0; c2 < 16; ++c2) s += red[i][c2];
        s += b_vg2[0];
        float gv = 1.0f / (1.0f + expf(-s));
        vg[b * L_ + l0 + i] = gv;
        vgs[i] = gv;
    } else if (i < 32){
        int t = i - 16;
        float s0 = 0.f, s1 = 0.f;
        #pragma unroll
        for (int c2 = 0; c2 < 16; ++c2){ s0 += red2[t][c2]; s1 += red3[t][c2]; }
        s0 += b_bg2[0]; s1 += b_bg2[1];
        float mx = fmaxf(s0, s1);
        float e0 = expf(s0 - mx), e1 = expf(s1 - mx);
        float inv = 1.0f / (e0 + e1);
        blend0[b * L_ + l0 + t] = e0 * inv;
        blend1[b * L_ + l0 + t] = e1 * inv;
    }
    __syncthreads();

    // gated kvv store (bf16, coalesced across d): thread = (tg, d)
    {
        int d = i & 255, tg = i >> 8;   // tg 0..1, 8 tokens each
        #pragma unroll
        for (int m = 0; m < 8; ++m){
            int tok = tg * 8 + m;
            kvvb[(size_t)(b * L_ + l0 + tok) * D_ + d] = f2bf(kvbuf[tok][d] * vgs[tok]);
        }
    }
}

// ---------------- K_scan1: chunk sums (NC=64, CL=32) + gatecum (z=8) ----------
__global__ __launch_bounds__(256) void k_scan1(
    const float* __restrict__ cpos, const float* __restrict__ spos,
    const float* __restrict__ ck, const float* __restrict__ sk,
    const unsigned short* __restrict__ pvb, const unsigned short* __restrict__ kvvb,
    const float* __restrict__ vg,
    float* __restrict__ posSr, float* __restrict__ posSi,
    float* __restrict__ kvSr, float* __restrict__ kvSi,
    float* __restrict__ rnorm)
{
    const int z = blockIdx.z;
    const int c = blockIdx.x, b = blockIdx.y;
    const int i = threadIdx.x;
    if (z == 8){
        if (c != 0) return;
        float loc[8];
        float run = 0.f;
        #pragma unroll
        for (int m = 0; m < 8; ++m){ run += vg[b * L_ + i * 8 + m]; loc[m] = run; }
        __shared__ float part[256];
        part[i] = run;
        __syncthreads();
        for (int off = 1; off < 256; off <<= 1){
            float t = (i >= off) ? part[i - off] : 0.0f;
            __syncthreads();
            part[i] += t;
            __syncthreads();
        }
        float excl = part[i] - run;
        #pragma unroll
        for (int m = 0; m < 8; ++m){
            float gc = fmaxf(excl + loc[m], 1.0f);
            rnorm[b * L_ + i * 8 + m] = rsqrtf(gc) * INV_SQRT_P;
        }
        return;
    }
    const int type = z >> 2, pg = z & 3;
    const int d = i;
    const int p0 = pg * 8;
    float Sr[8], Si[8];
    #pragma unroll
    for (int j = 0; j < 8; ++j){ Sr[j] = 0.f; Si[j] = 0.f; }

    if (type == 0){
        for (int l = 0; l < CL_; ++l){
            int row = c * CL_ + l;
            float v = bf2f(pvb[(size_t)(b * L_ + row) * D_ + d]);
            float4 c0 = *(const float4*)(cpos + row * P_ + p0);
            float4 c1 = *(const float4*)(cpos + row * P_ + p0 + 4);
            float4 s0 = *(const float4*)(spos + row * P_ + p0);
            float4 s1 = *(const float4*)(spos + row * P_ + p0 + 4);
            Sr[0] = fmaf(c0.x, v, Sr[0]); Si[0] = fmaf(s0.x, v, Si[0]);
            Sr[1] = fmaf(c0.y, v, Sr[1]); Si[1] = fmaf(s0.y, v, Si[1]);
            Sr[2] = fmaf(c0.z, v, Sr[2]); Si[2] = fmaf(s0.z, v, Si[2]);
            Sr[3] = fmaf(c0.w, v, Sr[3]); Si[3] = fmaf(s0.w, v, Si[3]);
            Sr[4] = fmaf(c1.x, v, Sr[4]); Si[4] = fmaf(s1.x, v, Si[4]);
            Sr[5] = fmaf(c1.y, v, Sr[5]); Si[5] = fmaf(s1.y, v, Si[5]);
            Sr[6] = fmaf(c1.z, v, Sr[6]); Si[6] = fmaf(s1.z, v, Si[6]);
            Sr[7] = fmaf(c1.w, v, Sr[7]); Si[7] = fmaf(s1.w, v, Si[7]);
        }
        #pragma unroll
        for (int j = 0; j < 8; ++j){
            size_t o = (size_t)((b * NC_ + c) * P_ + p0 + j) * D_ + d;
            posSr[o] = Sr[j]; posSi[o] = Si[j];
        }
    } else {
        float pc[8], ps[8];
        int srow = c * CL_ - 1;
        if (srow >= 0){
            float4 c0 = *(const float4*)(ck + ((size_t)b * L_ + srow) * P_ + p0);
            float4 c1 = *(const float4*)(ck + ((size_t)b * L_ + srow) * P_ + p0 + 4);
            float4 s0 = *(const float4*)(sk + ((size_t)b * L_ + srow) * P_ + p0);
            float4 s1 = *(const float4*)(sk + ((size_t)b * L_ + srow) * P_ + p0 + 4);
            pc[0]=c0.x; pc[1]=c0.y; pc[2]=c0.z; pc[3]=c0.w;
            pc[4]=c1.x; pc[5]=c1.y; pc[6]=c1.z; pc[7]=c1.w;
            ps[0]=s0.x; ps[1]=s0.y; ps[2]=s0.z; ps[3]=s0.w;
            ps[4]=s1.x; ps[5]=s1.y; ps[6]=s1.z; ps[7]=s1.w;
        } else {
            #pragma unroll
            for (int j = 0; j < 8; ++j){ pc[j] = 0.f; ps[j] = 0.f; }
        }
        for (int l = 0; l < CL_; ++l){
            int row = c * CL_ + l;
            float vv = bf2f(kvvb[(size_t)(b * L_ + row) * D_ + d]);  // pre-gated
            float4 c0 = *(const float4*)(ck + ((size_t)b * L_ + row) * P_ + p0);
            float4 c1 = *(const float4*)(ck + ((size_t)b * L_ + row) * P_ + p0 + 4);
            float4 s0 = *(const float4*)(sk + ((size_t)b * L_ + row) * P_ + p0);
            float4 s1 = *(const float4*)(sk + ((size_t)b * L_ + row) * P_ + p0 + 4);
            #pragma unroll
            for (int j = 0; j < 8; ++j){
                Sr[j] = fmaf(pc[j], vv, Sr[j]);
                Si[j] = fmaf(ps[j], vv, Si[j]);
            }
            pc[0]=c0.x; pc[1]=c0.y; pc[2]=c0.z; pc[3]=c0.w;
            pc[4]=c1.x; pc[5]=c1.y; pc[6]=c1.z; pc[7]=c1.w;
            ps[0]=s0.x; ps[1]=s0.y; ps[2]=s0.z; ps[3]=s0.w;
            ps[4]=s1.x; ps[5]=s1.y; ps[6]=s1.z; ps[7]=s1.w;
        }
        #pragma unroll
        for (int j = 0; j < 8; ++j){
            size_t o = (size_t)((b * NC_ + c) * P_ + p0 + j) * D_ + d;
            kvSr[o] = Sr[j]; kvSi[o] = Si[j];
        }
    }
}

// ---------------- K_prefix: exclusive prefix over 64 chunks, float4, 8-seg ----
__global__ __launch_bounds__(256) void k_prefix(
    float* __restrict__ posSr, float* __restrict__ posSi,
    float* __restrict__ kvSr, float* __restrict__ kvSi)
{
    __shared__ float4 tot_s[32][8];
    const int colLocal = threadIdx.x >> 3, seg = threadIdx.x & 7;
    const int col = blockIdx.x * 32 + colLocal;
    const int a = col >> 12;
    const int rem = col & 4095;
    const int b = rem >> 11;
    const int pd = (rem & 2047) * 4;
    float* A = (a == 0) ? posSr : (a == 1) ? posSi : (a == 2) ? kvSr : kvSi;
    float* base = A + (size_t)b * NC_ * (P_ * D_) + pd;

    float4 t[8];
    #pragma unroll
    for (int k = 0; k < 8; ++k)
        t[k] = *(const float4*)(base + (size_t)(seg * 8 + k) * (P_ * D_));
    float4 tot = {0.f, 0.f, 0.f, 0.f};
    #pragma unroll
    for (int k = 0; k < 8; ++k){
        tot.x += t[k].x; tot.y += t[k].y; tot.z += t[k].z; tot.w += t[k].w;
    }
    tot_s[colLocal][seg] = tot;
    __syncthreads();
    float4 run = {0.f, 0.f, 0.f, 0.f};
    #pragma unroll
    for (int s = 0; s < 7; ++s){
        if (s < seg){
            float4 v = tot_s[colLocal][s];
            run.x += v.x; run.y += v.y; run.z += v.z; run.w += v.w;
        }
    }
    #pragma unroll
    for (int k = 0; k < 8; ++k){
        float4 cur = t[k];
        *(float4*)(base + (size_t)(seg * 8 + k) * (P_ * D_)) = run;
        run.x += cur.x; run.y += cur.y; run.z += cur.z; run.w += cur.w;
    }
}

// ---------------- K_retrieve: P split 4-way across lanes, shfl reduce --------
__global__ __launch_bounds__(256) void k_retrieve(
    const float* __restrict__ cpos, const float* __restrict__ spos,
    const float* __restrict__ ck, const float* __restrict__ sk,
    const unsigned short* __restrict__ pvb, const unsigned short* __restrict__ kvvb,
    const float* __restrict__ rnorm,
    const float* __restrict__ posSr, const float* __restrict__ posSi,
    const float* __restrict__ kvSr, const float* __restrict__ kvSi,
    unsigned short* __restrict__ posretb, unsigned short* __restrict__ kvretb)
{
    const int z = blockIdx.z;
    const int c = blockIdx.x, b = blockIdx.y;
    const int type = z >> 2, dquad = z & 3;
    const int lane = threadIdx.x & 63, wv = threadIdx.x >> 6;
    const int pg = lane >> 4, dl = lane & 15;
    const int d = dquad * 64 + wv * 16 + dl;
    const int p0 = pg * 8;

    float Sr[8], Si[8];

    if (type == 0){
        #pragma unroll
        for (int j = 0; j < 8; ++j){
            size_t o = (size_t)((b * NC_ + c) * P_ + p0 + j) * D_ + d;
            Sr[j] = posSr[o]; Si[j] = posSi[o];
        }
        for (int l = 0; l < CL_; ++l){
            int row = c * CL_ + l;
            float v = bf2f(pvb[(size_t)(b * L_ + row) * D_ + d]);
            float4 c0 = *(const float4*)(cpos + row * P_ + p0);
            float4 c1 = *(const float4*)(cpos + row * P_ + p0 + 4);
            float4 s0 = *(const float4*)(spos + row * P_ + p0);
            float4 s1 = *(const float4*)(spos + row * P_ + p0 + 4);
            float r0 = 0.f, r1 = 0.f, r2 = 0.f, r3 = 0.f;
            Sr[0] = fmaf(c0.x, v, Sr[0]); r0 = fmaf(c0.x, Sr[0], r0);
            Si[0] = fmaf(s0.x, v, Si[0]); r1 = fmaf(s0.x, Si[0], r1);
            Sr[1] = fmaf(c0.y, v, Sr[1]); r2 = fmaf(c0.y, Sr[1], r2);
            Si[1] = fmaf(s0.y, v, Si[1]); r3 = fmaf(s0.y, Si[1], r3);
            Sr[2] = fmaf(c0.z, v, Sr[2]); r0 = fmaf(c0.z, Sr[2], r0);
            Si[2] = fmaf(s0.z, v, Si[2]); r1 = fmaf(s0.z, Si[2], r1);
            Sr[3] = fmaf(c0.w, v, Sr[3]); r2 = fmaf(c0.w, Sr[3], r2);
            Si[3] = fmaf(s0.w, v, Si[3]); r3 = fmaf(s0.w, Si[3], r3);
            Sr[4] = fmaf(c1.x, v, Sr[4]); r0 = fmaf(c1.x, Sr[4], r0);
            Si[4] = fmaf(s1.x, v, Si[4]); r1 = fmaf(s1.x, Si[4], r1);
            Sr[5] = fmaf(c1.y, v, Sr[5]); r2 = fmaf(c1.y, Sr[5], r2);
            Si[5] = fmaf(s1.y, v, Si[5]); r3 = fmaf(s1.y, Si[5], r3);
            Sr[6] = fmaf(c1.z, v, Sr[6]); r0 = fmaf(c1.z, Sr[6], r0);
            Si[6] = fmaf(s1.z, v, Si[6]); r1 = fmaf(s1.z, Si[6], r1);
            Sr[7] = fmaf(c1.w, v, Sr[7]); r2 = fmaf(c1.w, Sr[7], r2);
            Si[7] = fmaf(s1.w, v, Si[7]); r3 = fmaf(s1.w, Si[7], r3);
            float r = (r0 + r1) + (r2 + r3);
            r += __shfl_xor(r, 16, 64);
            r += __shfl_xor(r, 32, 64);
            if (pg == 0)
                posretb[(size_t)(b * L_ + row) * D_ + d] = f2bf(r * INV_SQRT_P);
        }
    } else {
        #pragma unroll
        for (int j = 0; j < 8; ++j){
            size_t o = (size_t)((b * NC_ + c) * P_ + p0 + j) * D_ + d;
            Sr[j] = kvSr[o]; Si[j] = kvSi[o];
        }
        float pc[8], ps[8];
        int srow = c * CL_ - 1;
        if (srow >= 0){
            float4 c0 = *(const float4*)(ck + ((size_t)b * L_ + srow) * P_ + p0);
            float4 c1 = *(const float4*)(ck + ((size_t)b * L_ + srow) * P_ + p0 + 4);
            float4 s0 = *(const float4*)(sk + ((size_t)b * L_ + srow) * P_ + p0);
            float4 s1 = *(const float4*)(sk + ((size_t)b * L_ + srow) * P_ + p0 + 4);
            pc[0]=c0.x; pc[1]=c0.y; pc[2]=c0.z; pc[3]=c0.w;
            pc[4]=c1.x; pc[5]=c1.y; pc[6]=c1.z; pc[7]=c1.w;
            ps[0]=s0.x; ps[1]=s0.y; ps[2]=s0.z; ps[3]=s0.w;
            ps[4]=s1.x; ps[5]=s1.y; ps[6]=s1.z; ps[7]=s1.w;
        } else {
            #pragma unroll
            for (int j = 0; j < 8; ++j){ pc[j] = 0.f; ps[j] = 0.f; }
        }
        for (int l = 0; l < CL_; ++l){
            int row = c * CL_ + l;
            float vv = bf2f(kvvb[(size_t)(b * L_ + row) * D_ + d]);  // pre-gated
            float rn = rnorm[b * L_ + row];
            float4 c0 = *(const float4*)(ck + ((size_t)b * L_ + row) * P_ + p0);
            float4 c1 = *(const float4*)(ck + ((size_t)b * L_ + row) * P_ + p0 + 4);
            float4 s0 = *(const float4*)(sk + ((size_t)b * L_ + row) * P_ + p0);
            float4 s1 = *(const float4*)(sk + ((size_t)b * L_ + row) * P_ + p0 + 4);
            float qc[8], qs[8];
            qc[0]=c0.x; qc[1]=c0.y; qc[2]=c0.z; qc[3]=c0.w;
            qc[4]=c1.x; qc[5]=c1.y; qc[6]=c1.z; qc[7]=c1.w;
            qs[0]=s0.x; qs[1]=s0.y; qs[2]=s0.z; qs[3]=s0.w;
            qs[4]=s1.x; qs[5]=s1.y; qs[6]=s1.z; qs[7]=s1.w;
            float r0 = 0.f, r1 = 0.f, r2 = 0.f, r3 = 0.f;
            #pragma unroll
            for (int j = 0; j < 8; ++j){
                Sr[j] = fmaf(pc[j], vv, Sr[j]);
                Si[j] = fmaf(ps[j], vv, Si[j]);
                if (j & 1){ r2 = fmaf(qc[j], Sr[j], r2); r3 = fmaf(qs[j], Si[j], r3); }
                else      { r0 = fmaf(qc[j], Sr[j], r0); r1 = fmaf(qs[j], Si[j], r1); }
                pc[j] = qc[j]; ps[j] = qs[j];
            }
            float r = (r0 + r1) + (r2 + r3);
            r += __shfl_xor(r, 16, 64);
            r += __shfl_xor(r, 32, 64);
            if (pg == 0)
                kvretb[(size_t)(b * L_ + row) * D_ + d] = f2bf(r * rn);
        }
    }
}

// ---------------- K9: blend -> LN -> r1 -> r2 -> LN -> out, 16 waves ---------
__global__ __launch_bounds__(1024) void k_final(
    const float* __restrict__ x,
    const unsigned short* __restrict__ posretb, const unsigned short* __restrict__ kvretb,
    const float* __restrict__ blend0, const float* __restrict__ blend1,
    const unsigned short* __restrict__ wq,
    const float* __restrict__ ln_r_g, const float* __restrict__ ln_r_b,
    const float* __restrict__ b_r1, const float* __restrict__ b_r2,
    const float* __restrict__ ln_o_g, const float* __restrict__ ln_o_b,
    const float* __restrict__ b_out,
    float* __restrict__ out)
{
    __shared__ float zbuf[16][257];
    __shared__ __align__(16) unsigned short aA[8][512];
    __shared__ __align__(16) unsigned short aH[16][512];
    __shared__ float red[16][17], red2[16][17];
    __shared__ float mu[16], rs[16];

    const int i = threadIdx.x, lane = i & 63, w = i >> 6;   // w 0..15
    const int b = blockIdx.x >> 7, l0 = (blockIdx.x & 127) * 16;
    const int g = lane >> 4, c = lane & 15;
    const unsigned short* wr1  = wq + 294912;
    const unsigned short* wr2  = wq + 425984;
    const unsigned short* wout = wq + 557056;

    // load bf16 posret/kvret + blend -> zbuf fp32 (threads 0..511)
    if (i < 512){
        int t = i >> 5, c0 = (i & 31) * 8;
        size_t base = (size_t)(b * L_ + l0 + t) * D_ + c0;
        float w0 = blend0[b * L_ + l0 + t], w1 = blend1[b * L_ + l0 + t];
        bf16x8 pp = *(const bf16x8*)(posretb + base);
        bf16x8 kk = *(const bf16x8*)(kvretb + base);
        #pragma unroll
        for (int m = 0; m < 8; ++m)
            zbuf[t][c0 + m] = w0 * bf2f((unsigned short)pp[m])
                            + w1 * bf2f((unsigned short)kk[m]);
    }
    __syncthreads();

    if (i < 256){
        int t = i >> 4, c2 = i & 15;
        float s = 0.f, s2 = 0.f;
        #pragma unroll
        for (int m = 0; m < 16; ++m){ float v = zbuf[t][c2 + 16 * m]; s += v; s2 += v * v; }
        red[t][c2] = s; red2[t][c2] = s2;
    }
    __syncthreads();
    if (i < 16){
        float s = 0.f, s2 = 0.f;
        #pragma unroll
        for (int c2 = 0; c2 < 16; ++c2){ s += red[i][c2]; s2 += red2[i][c2]; }
        float mean = s * (1.0f / 256.0f);
        float var  = s2 * (1.0f / 256.0f) - mean * mean;
        mu[i] = mean; rs[i] = rsqrtf(var + 1e-5f);
    }
    __syncthreads();

    // repack LN1 -> aA (threads 0..511)
    if (i < 512){
        int kt = i >> 6;
        int t2 = lane & 15, kb = kt * 32 + ((lane >> 4) << 3);
        float m_ = mu[t2], r_ = rs[t2];
        bf16x8 v8;
        #pragma unroll
        for (int j = 0; j < 8; ++j){
            int k = kb + j;
            float v = (zbuf[t2][k] - m_) * r_ * ln_r_g[k] + ln_r_b[k];
            v8[j] = (short)f2bf(v);
        }
        *(bf16x8*)&aA[kt][lane * 8] = v8;
    }
    __syncthreads();

    // r1: 32 N-tiles over 16 waves (2 each)
    {
        bf16x8 afr[8];
        #pragma unroll
        for (int kt = 0; kt < 8; ++kt) afr[kt] = *(const bf16x8*)&aA[kt][lane * 8];
        #pragma unroll
        for (int q = 0; q < 2; ++q){
            int nt = w + 16 * q;
            f32x4 acc = {0.f, 0.f, 0.f, 0.f};
            #pragma unroll
            for (int kt = 0; kt < 8; ++kt){
                bf16x8 bf = *(const bf16x8*)(wr1 + (kt * 32 + nt) * 512 + lane * 8);
                acc = __builtin_amdgcn_mfma_f32_16x16x32_bf16(afr[kt], bf, acc, 0, 0, 0);
            }
            float bb = b_r1[nt * 16 + c];
            #pragma unroll
            for (int r = 0; r < 4; ++r){
                float hv = gelu_exact(acc[r] + bb);
                int t = 4 * g + r, hcol = nt * 16 + c;
                int kt2 = hcol >> 5, kk = hcol & 31;
                int lane2 = ((kk >> 3) << 4) + t, j2 = kk & 7;
                aH[kt2][lane2 * 8 + j2] = f2bf(hv);
            }
        }
    }
    __syncthreads();

    // r2: 16 N-tiles over 16 waves (1 each), K=512
    {
        int nt = w;
        f32x4 acc = {0.f, 0.f, 0.f, 0.f};
        #pragma unroll
        for (int kt = 0; kt < 16; ++kt){
            bf16x8 hfr = *(const bf16x8*)&aH[kt][lane * 8];
            bf16x8 bf = *(const bf16x8*)(wr2 + (kt * 16 + nt) * 512 + lane * 8);
            acc = __builtin_amdgcn_mfma_f32_16x16x32_bf16(hfr, bf, acc, 0, 0, 0);
        }
        float bb = b_r2[nt * 16 + c];
        #pragma unroll
        for (int r = 0; r < 4; ++r)
            zbuf[4 * g + r][nt * 16 + c] = acc[r] + bb;
    }
    __syncthreads();

    if (i < 256){
        int t = i >> 4, c2 = i & 15;
        float s = 0.f, s2 = 0.f;
        #pragma unroll
        for (int m = 0; m < 16; ++m){ float v = zbuf[t][c2 + 16 * m]; s += v; s2 += v * v; }
        red[t][c2] = s; red2[t][c2] = s2;
    }
    __syncthreads();
    if (i < 16){
        float s = 0.f, s2 = 0.f;
        #pragma unroll
        for (int c2 = 0; c2 < 16; ++c2){ s += red[i][c2]; s2 += red2[i][c2]; }
        float mean = s * (1.0f / 256.0f);
        float var  = s2 * (1.0f / 256.0f) - mean * mean;
        mu[i] = mean; rs[i] = rsqrtf(var + 1e-5f);
    }
    __syncthreads();

    // repack LN2 -> aA (threads 0..511)
    if (i < 512){
        int kt = i >> 6;
        int t2 = lane & 15, kb = kt * 32 + ((lane >> 4) << 3);
        float m_ = mu[t2], r_ = rs[t2];
        bf16x8 v8;
        #pragma unroll
        for (int j = 0; j < 8; ++j){
            int k = kb + j;
            float v = (zbuf[t2][k] - m_) * r_ * ln_o_g[k] + ln_o_b[k];
            v8[j] = (short)f2bf(v);
        }
        *(bf16x8*)&aA[kt][lane * 8] = v8;
    }
    __syncthreads();

    // out: 16 N-tiles over 16 waves (1 each) + residual
    {
        int nt = w;
        f32x4 acc = {0.f, 0.f, 0.f, 0.f};
        #pragma unroll
        for (int kt = 0; kt < 8; ++kt){
            bf16x8 azr = *(const bf16x8*)&aA[kt][lane * 8];
            bf16x8 bf = *(const bf16x8*)(wout + (kt * 16 + nt) * 512 + lane * 8);
            acc = __builtin_amdgcn_mfma_f32_16x16x32_bf16(azr, bf, acc, 0, 0, 0);
        }
        float bb = b_out[nt * 16 + c];
        #pragma unroll
        for (int r = 0; r < 4; ++r){
            size_t o = (size_t)(b * L_ + l0 + 4 * g + r) * D_ + nt * 16 + c;
            out[o] = x[o] + acc[r] + bb;
        }
    }
}

extern "C" void kernel_launch(void* const* d_in, const int* in_sizes, int n_in,
                              void* d_out, int out_size, void* d_ws, size_t ws_size,
                              hipStream_t stream) {
    const float* x          = (const float*)d_in[0];
    const float* pos_phases = (const float*)d_in[1];
    const float* w_pv       = (const float*)d_in[2];
    const float* b_pv       = (const float*)d_in[3];
    const float* w_key      = (const float*)d_in[4];
    const float* b_key      = (const float*)d_in[5];
    const float* w_kv       = (const float*)d_in[6];
    const float* b_kv       = (const float*)d_in[7];
    const float* w_vg1      = (const float*)d_in[8];
    const float* b_vg1      = (const float*)d_in[9];
    const float* w_vg2      = (const float*)d_in[10];
    const float* b_vg2      = (const float*)d_in[11];
    const float* w_bg1      = (const float*)d_in[12];
    const float* b_bg1      = (const float*)d_in[13];
    const float* w_bg2      = (const float*)d_in[14];
    const float* b_bg2      = (const float*)d_in[15];
    const float* ln_r_g     = (const float*)d_in[16];
    const float* ln_r_b     = (const float*)d_in[17];
    const float* w_r1       = (const float*)d_in[18];
    const float* b_r1       = (const float*)d_in[19];
    const float* w_r2       = (const float*)d_in[20];
    const float* b_r2       = (const float*)d_in[21];
    const float* ln_o_g     = (const float*)d_in[22];
    const float* ln_o_b     = (const float*)d_in[23];
    const float* w_out      = (const float*)d_in[24];
    const float* b_out      = (const float*)d_in[25];
    float* out = (float*)d_out;

    float* ws = (float*)d_ws;
    size_t off = 0;
    float* cpos   = ws + off; off += (size_t)L_ * P_;
    float* spos   = ws + off; off += (size_t)L_ * P_;
    float* ck     = ws + off; off += (size_t)B_ * L_ * P_;
    float* sk     = ws + off; off += (size_t)B_ * L_ * P_;
    float* vg     = ws + off; off += (size_t)B_ * L_;
    float* rnorm  = ws + off; off += (size_t)B_ * L_;
    float* blend0 = ws + off; off += (size_t)B_ * L_;
    float* blend1 = ws + off; off += (size_t)B_ * L_;
    float* posSr  = ws + off; off += (size_t)B_ * NC_ * P_ * D_;
    float* posSi  = ws + off; off += (size_t)B_ * NC_ * P_ * D_;
    float* kvSr   = ws + off; off += (size_t)B_ * NC_ * P_ * D_;
    float* kvSi   = ws + off; off += (size_t)B_ * NC_ * P_ * D_;
    unsigned short* wq      = (unsigned short*)(ws + off); off += 630784 / 2;
    unsigned short* pvb     = (unsigned short*)(ws + off); off += (size_t)B_ * L_ * D_ / 2;
    unsigned short* kvvb    = (unsigned short*)(ws + off); off += (size_t)B_ * L_ * D_ / 2;
    unsigned short* posretb = (unsigned short*)(ws + off); off += (size_t)B_ * L_ * D_ / 2;
    unsigned short* kvretb  = (unsigned short*)(ws + off); off += (size_t)B_ * L_ * D_ / 2;

    k_prep<<<2720, 256, 0, stream>>>(pos_phases,
        w_pv, w_kv, w_vg1, w_bg1, w_r1, w_r2, w_out, w_key,
        wq, cpos, spos);

    k_proj<<<B_ * 128, 512, 0, stream>>>(x, wq,
        b_pv, b_kv, b_vg1, w_vg2, b_vg2, b_bg1, w_bg2, b_bg2, b_key,
        pvb, kvvb, ck, sk, vg, blend0, blend1);

    k_scan1<<<dim3(NC_, B_, 9), 256, 0, stream>>>(cpos, spos, ck, sk, pvb, kvvb, vg,
                                                  posSr, posSi, kvSr, kvSi, rnorm);

    k_prefix<<<512, 256, 0, stream>>>(posSr, posSi, kvSr, kvSi);

    k_retrieve<<<dim3(NC_, B_, 8), 256, 0, stream>>>(cpos, spos, ck, sk, pvb, kvvb,
                                                     rnorm,
                                                     posSr, posSi, kvSr, kvSi,
                                                     posretb, kvretb);

    k_final<<<B_ * 128, 1024, 0, stream>>>(x, posretb, kvretb, blend0, blend1, wq,
        ln_r_g, ln_r_b, b_r1, b_r2, ln_o_g, ln_o_b, b_out, out);
}

// Round 16
// 85.854 us; speedup vs baseline: 1.0598x; 1.0598x over previous
//
#include <hip/hip_runtime.h>
#include <math.h>

#define B_ 2
#define L_ 2048
#define D_ 256
#define P_ 32
#define NC_ 64
#define CL_ 32

#define INV_SQRT_P 0.17677669529663687f   // 1/sqrt(32)
#define PI_F 3.14159265358979323846f

typedef __attribute__((ext_vector_type(8))) short bf16x8;
typedef __attribute__((ext_vector_type(4))) float f32x4;

__device__ __forceinline__ float gelu_exact(float x){
    return 0.5f * x * (1.0f + erff(x * 0.70710678118654752f));
}

__device__ __forceinline__ unsigned short f2bf(float f){
    unsigned int u = __float_as_uint(f);
    u += 0x7FFFu + ((u >> 16) & 1u);     // round-to-nearest-even
    return (unsigned short)(u >> 16);
}

__device__ __forceinline__ float bf2f(unsigned short u){
    return __uint_as_float(((unsigned int)u) << 16);
}

// ---------------- K_prep: weight bf16 repacks + pos sincos ----------
__global__ __launch_bounds__(256) void k_prep(
    const float* __restrict__ pos_phases,
    const float* __restrict__ w_pv, const float* __restrict__ w_kv,
    const float* __restrict__ w_vg1, const float* __restrict__ w_bg1,
    const float* __restrict__ w_r1, const float* __restrict__ w_r2,
    const float* __restrict__ w_out, const float* __restrict__ w_key,
    unsigned short* __restrict__ wq,
    float* __restrict__ cpos, float* __restrict__ spos)
{
    int id = blockIdx.x * 256 + threadIdx.x;   // 0..696319
    if (id < 630784){
        const float* src; int N; int local;
        if (id < 65536)       { src = w_pv;  N = 256; local = id; }
        else if (id < 131072) { src = w_kv;  N = 256; local = id - 65536; }
        else if (id < 262144) { src = w_vg1; N = 256; local = id - 131072; }
        else if (id < 294912) { src = w_bg1; N = 128; local = id - 262144; }
        else if (id < 425984) { src = w_r1;  N = 512; local = id - 294912; }
        else if (id < 557056) { src = w_r2;  N = 256; local = id - 425984; }
        else if (id < 622592) { src = w_out; N = 256; local = id - 557056; }
        else                  { src = w_key; N = 32;  local = id - 622592; }
        int j = local & 7, lane = (local >> 3) & 63, tile = local >> 9;
        int NT = N >> 4;
        int nt = tile % NT, kt = tile / NT;
        int row = kt * 32 + ((lane >> 4) << 3) + j;
        int col = nt * 16 + (lane & 15);
        wq[id] = f2bf(src[(size_t)row * N + col]);
    } else {
        int idx = id - 630784;                 // 0..65535 = L*P
        float s, c;
        sincosf(pos_phases[idx], &s, &c);
        cpos[idx] = c;
        spos[idx] = s;
    }
}

// ---------------- K1: fused projections via MFMA, 16 tokens/block, 8 waves ----
__global__ __launch_bounds__(512) void k_proj(
    const float* __restrict__ x,
    const unsigned short* __restrict__ wq,
    const float* __restrict__ b_pv, const float* __restrict__ b_kv,
    const float* __restrict__ b_vg1,
    const float* __restrict__ w_vg2, const float* __restrict__ b_vg2,
    const float* __restrict__ b_bg1,
    const float* __restrict__ w_bg2, const float* __restrict__ b_bg2,
    const float* __restrict__ b_key,
    unsigned short* __restrict__ pvb, unsigned short* __restrict__ kvvb,
    float* __restrict__ ck, float* __restrict__ sk,
    float* __restrict__ vg, float* __restrict__ blend0, float* __restrict__ blend1)
{
    __shared__ float hbuf[16][257];
    __shared__ float kvbuf[16][257];
    __shared__ float bhbuf[16][129];
    __shared__ float kph[16][33];
    __shared__ float red[16][17], red2[16][17], red3[16][17];
    __shared__ float vgs[16];

    const int i = threadIdx.x;
    const int lane = i & 63, w = i >> 6;
    const int b = blockIdx.x >> 7, lt = blockIdx.x & 127, l0 = lt * 16;
    const int g = lane >> 4, c = lane & 15;

    // pack A fragments (x and shifted-x) directly from x
    bf16x8 xa[8], xs[8];
    {
        int row  = l0 + (lane & 15);
        int rowp = row - 1;
        const float* xr = x + (size_t)(b * L_ + row) * D_ + ((lane >> 4) << 3);
        #pragma unroll
        for (int kt = 0; kt < 8; ++kt){
            float4 a0 = *(const float4*)(xr + kt * 32);
            float4 a1 = *(const float4*)(xr + kt * 32 + 4);
            bf16x8 v;
            v[0] = (short)f2bf(a0.x); v[1] = (short)f2bf(a0.y);
            v[2] = (short)f2bf(a0.z); v[3] = (short)f2bf(a0.w);
            v[4] = (short)f2bf(a1.x); v[5] = (short)f2bf(a1.y);
            v[6] = (short)f2bf(a1.z); v[7] = (short)f2bf(a1.w);
            xa[kt] = v;
        }
        if (rowp >= 0){
            const float* xp = x + (size_t)(b * L_ + rowp) * D_ + ((lane >> 4) << 3);
            #pragma unroll
            for (int kt = 0; kt < 8; ++kt){
                float4 a0 = *(const float4*)(xp + kt * 32);
                float4 a1 = *(const float4*)(xp + kt * 32 + 4);
                bf16x8 v;
                v[0] = (short)f2bf(a0.x); v[1] = (short)f2bf(a0.y);
                v[2] = (short)f2bf(a0.z); v[3] = (short)f2bf(a0.w);
                v[4] = (short)f2bf(a1.x); v[5] = (short)f2bf(a1.y);
                v[6] = (short)f2bf(a1.z); v[7] = (short)f2bf(a1.w);
                xs[kt] = v;
            }
        } else {
            #pragma unroll
            for (int kt = 0; kt < 8; ++kt){
                bf16x8 v;
                #pragma unroll
                for (int j = 0; j < 8; ++j) v[j] = 0;
                xs[kt] = v;
            }
        }
    }

    const unsigned short* wpv  = wq;
    const unsigned short* wkv  = wq + 65536;
    const unsigned short* wvg1 = wq + 131072;
    const unsigned short* wbg1 = wq + 262144;
    const unsigned short* wkey = wq + 622592;

    // 58 tile jobs: [0,2) key, [2,18) pv, [18,34) kv, [34,50) vg1(K=512), [50,58) bg1
    for (int jb = w; jb < 58; jb += 8){
        f32x4 acc = {0.f, 0.f, 0.f, 0.f};
        if (jb < 2){
            int nt = jb;
            #pragma unroll
            for (int kt = 0; kt < 8; ++kt){
                bf16x8 bf = *(const bf16x8*)(wkey + (kt * 2 + nt) * 512 + lane * 8);
                acc = __builtin_amdgcn_mfma_f32_16x16x32_bf16(xa[kt], bf, acc, 0, 0, 0);
            }
            float bb = b_key[nt * 16 + c];
            #pragma unroll
            for (int r = 0; r < 4; ++r)
                kph[4 * g + r][nt * 16 + c] = acc[r] + bb;
        } else if (jb < 18){
            int nt = jb - 2;
            #pragma unroll
            for (int kt = 0; kt < 8; ++kt){
                bf16x8 bf = *(const bf16x8*)(wpv + (kt * 16 + nt) * 512 + lane * 8);
                acc = __builtin_amdgcn_mfma_f32_16x16x32_bf16(xa[kt], bf, acc, 0, 0, 0);
            }
            float bb = b_pv[nt * 16 + c];
            #pragma unroll
            for (int r = 0; r < 4; ++r)
                pvb[(size_t)(b * L_ + l0 + 4 * g + r) * D_ + nt * 16 + c] = f2bf(acc[r] + bb);
        } else if (jb < 34){
            int nt = jb - 18;
            #pragma unroll
            for (int kt = 0; kt < 8; ++kt){
                bf16x8 bf = *(const bf16x8*)(wkv + (kt * 16 + nt) * 512 + lane * 8);
                acc = __builtin_amdgcn_mfma_f32_16x16x32_bf16(xa[kt], bf, acc, 0, 0, 0);
            }
            float bb = b_kv[nt * 16 + c];
            #pragma unroll
            for (int r = 0; r < 4; ++r)
                kvbuf[4 * g + r][nt * 16 + c] = acc[r] + bb;
        } else if (jb < 50){
            int nt = jb - 34;
            #pragma unroll
            for (int kt = 0; kt < 8; ++kt){
                bf16x8 bf = *(const bf16x8*)(wvg1 + (kt * 16 + nt) * 512 + lane * 8);
                acc = __builtin_amdgcn_mfma_f32_16x16x32_bf16(xa[kt], bf, acc, 0, 0, 0);
            }
            #pragma unroll
            for (int kt = 8; kt < 16; ++kt){
                bf16x8 bf = *(const bf16x8*)(wvg1 + (kt * 16 + nt) * 512 + lane * 8);
                acc = __builtin_amdgcn_mfma_f32_16x16x32_bf16(xs[kt - 8], bf, acc, 0, 0, 0);
            }
            float bb = b_vg1[nt * 16 + c];
            #pragma unroll
            for (int r = 0; r < 4; ++r)
                hbuf[4 * g + r][nt * 16 + c] = gelu_exact(acc[r] + bb);
        } else {
            int nt = jb - 50;
            #pragma unroll
            for (int kt = 0; kt < 8; ++kt){
                bf16x8 bf = *(const bf16x8*)(wbg1 + (kt * 8 + nt) * 512 + lane * 8);
                acc = __builtin_amdgcn_mfma_f32_16x16x32_bf16(xa[kt], bf, acc, 0, 0, 0);
            }
            float bb = b_bg1[nt * 16 + c];
            #pragma unroll
            for (int r = 0; r < 4; ++r)
                bhbuf[4 * g + r][nt * 16 + c] = gelu_exact(acc[r] + bb);
        }
    }
    __syncthreads();

    // key phases -> phasors (fp32)
    {
        int t = i >> 5, p = i & 31;
        float a = tanhf(kph[t][p]) * PI_F;
        float s, cc;
        sincosf(a, &s, &cc);
        ck[(size_t)(b * L_ + l0 + t) * P_ + p] = cc;
        sk[(size_t)(b * L_ + l0 + t) * P_ + p] = s;
    }

    // vg2 (threads 0..255) and bg2 (threads 256..511) partial reductions
    if (i < 256){
        int t = i >> 4, c2 = i & 15;
        float s = 0.f;
        #pragma unroll
        for (int m = 0; m < 16; ++m){ int dd = c2 + 16 * m; s += hbuf[t][dd] * w_vg2[dd]; }
        red[t][c2] = s;
    } else {
        int ii = i - 256;
        int t = ii >> 4, c2 = ii & 15;
        float s0 = 0.f, s1 = 0.f;
        #pragma unroll
        for (int m = 0; m < 8; ++m){
            int jj = c2 + 16 * m;
            float v = bhbuf[t][jj];
            s0 += v * w_bg2[jj * 2 + 0];
            s1 += v * w_bg2[jj * 2 + 1];
        }
        red2[t][c2] = s0; red3[t][c2] = s1;
    }
    __syncthreads();
    if (i < 16){
        float s = 0.f;
        #pragma unroll
        for (int c2 = 0; c2 < 16; ++c2) s += red[i][c2];
        s += b_vg2[0];
        float gv = 1.0f / (1.0f + expf(-s));
        vg[b * L_ + l0 + i] = gv;
        vgs[i] = gv;
    } else if (i < 32){
        int t = i - 16;
        float s0 = 0.f, s1 = 0.f;
        #pragma unroll
        for (int c2 = 0; c2 < 16; ++c2){ s0 += red2[t][c2]; s1 += red3[t][c2]; }
        s0 += b_bg2[0]; s1 += b_bg2[1];
        float mx = fmaxf(s0, s1);
        float e0 = expf(s0 - mx), e1 = expf(s1 - mx);
        float inv = 1.0f / (e0 + e1);
        blend0[b * L_ + l0 + t] = e0 * inv;
        blend1[b * L_ + l0 + t] = e1 * inv;
    }
    __syncthreads();

    // gated kvv store (bf16, coalesced across d): thread = (tg, d)
    {
        int d = i & 255, tg = i >> 8;   // tg 0..1, 8 tokens each
        #pragma unroll
        for (int m = 0; m < 8; ++m){
            int tok = tg * 8 + m;
            kvvb[(size_t)(b * L_ + l0 + tok) * D_ + d] = f2bf(kvbuf[tok][d] * vgs[tok]);
        }
    }
}

// ---------------- K_scan1: chunk sums (NC=64, CL=32) + gatecum (z=8) ----------
__global__ __launch_bounds__(256) void k_scan1(
    const float* __restrict__ cpos, const float* __restrict__ spos,
    const float* __restrict__ ck, const float* __restrict__ sk,
    const unsigned short* __restrict__ pvb, const unsigned short* __restrict__ kvvb,
    const float* __restrict__ vg,
    float* __restrict__ posSr, float* __restrict__ posSi,
    float* __restrict__ kvSr, float* __restrict__ kvSi,
    float* __restrict__ rnorm)
{
    const int z = blockIdx.z;
    const int c = blockIdx.x, b = blockIdx.y;
    const int i = threadIdx.x;
    if (z == 8){
        if (c != 0) return;
        float loc[8];
        float run = 0.f;
        #pragma unroll
        for (int m = 0; m < 8; ++m){ run += vg[b * L_ + i * 8 + m]; loc[m] = run; }
        __shared__ float part[256];
        part[i] = run;
        __syncthreads();
        for (int off = 1; off < 256; off <<= 1){
            float t = (i >= off) ? part[i - off] : 0.0f;
            __syncthreads();
            part[i] += t;
            __syncthreads();
        }
        float excl = part[i] - run;
        #pragma unroll
        for (int m = 0; m < 8; ++m){
            float gc = fmaxf(excl + loc[m], 1.0f);
            rnorm[b * L_ + i * 8 + m] = rsqrtf(gc) * INV_SQRT_P;
        }
        return;
    }
    const int type = z >> 2, pg = z & 3;
    const int d = i;
    const int p0 = pg * 8;
    float Sr[8], Si[8];
    #pragma unroll
    for (int j = 0; j < 8; ++j){ Sr[j] = 0.f; Si[j] = 0.f; }

    if (type == 0){
        for (int l = 0; l < CL_; ++l){
            int row = c * CL_ + l;
            float v = bf2f(pvb[(size_t)(b * L_ + row) * D_ + d]);
            float4 c0 = *(const float4*)(cpos + row * P_ + p0);
            float4 c1 = *(const float4*)(cpos + row * P_ + p0 + 4);
            float4 s0 = *(const float4*)(spos + row * P_ + p0);
            float4 s1 = *(const float4*)(spos + row * P_ + p0 + 4);
            Sr[0] = fmaf(c0.x, v, Sr[0]); Si[0] = fmaf(s0.x, v, Si[0]);
            Sr[1] = fmaf(c0.y, v, Sr[1]); Si[1] = fmaf(s0.y, v, Si[1]);
            Sr[2] = fmaf(c0.z, v, Sr[2]); Si[2] = fmaf(s0.z, v, Si[2]);
            Sr[3] = fmaf(c0.w, v, Sr[3]); Si[3] = fmaf(s0.w, v, Si[3]);
            Sr[4] = fmaf(c1.x, v, Sr[4]); Si[4] = fmaf(s1.x, v, Si[4]);
            Sr[5] = fmaf(c1.y, v, Sr[5]); Si[5] = fmaf(s1.y, v, Si[5]);
            Sr[6] = fmaf(c1.z, v, Sr[6]); Si[6] = fmaf(s1.z, v, Si[6]);
            Sr[7] = fmaf(c1.w, v, Sr[7]); Si[7] = fmaf(s1.w, v, Si[7]);
        }
        #pragma unroll
        for (int j = 0; j < 8; ++j){
            size_t o = (size_t)((b * NC_ + c) * P_ + p0 + j) * D_ + d;
            posSr[o] = Sr[j]; posSi[o] = Si[j];
        }
    } else {
        float pc[8], ps[8];
        int srow = c * CL_ - 1;
        if (srow >= 0){
            float4 c0 = *(const float4*)(ck + ((size_t)b * L_ + srow) * P_ + p0);
            float4 c1 = *(const float4*)(ck + ((size_t)b * L_ + srow) * P_ + p0 + 4);
            float4 s0 = *(const float4*)(sk + ((size_t)b * L_ + srow) * P_ + p0);
            float4 s1 = *(const float4*)(sk + ((size_t)b * L_ + srow) * P_ + p0 + 4);
            pc[0]=c0.x; pc[1]=c0.y; pc[2]=c0.z; pc[3]=c0.w;
            pc[4]=c1.x; pc[5]=c1.y; pc[6]=c1.z; pc[7]=c1.w;
            ps[0]=s0.x; ps[1]=s0.y; ps[2]=s0.z; ps[3]=s0.w;
            ps[4]=s1.x; ps[5]=s1.y; ps[6]=s1.z; ps[7]=s1.w;
        } else {
            #pragma unroll
            for (int j = 0; j < 8; ++j){ pc[j] = 0.f; ps[j] = 0.f; }
        }
        for (int l = 0; l < CL_; ++l){
            int row = c * CL_ + l;
            float vv = bf2f(kvvb[(size_t)(b * L_ + row) * D_ + d]);  // pre-gated
            float4 c0 = *(const float4*)(ck + ((size_t)b * L_ + row) * P_ + p0);
            float4 c1 = *(const float4*)(ck + ((size_t)b * L_ + row) * P_ + p0 + 4);
            float4 s0 = *(const float4*)(sk + ((size_t)b * L_ + row) * P_ + p0);
            float4 s1 = *(const float4*)(sk + ((size_t)b * L_ + row) * P_ + p0 + 4);
            #pragma unroll
            for (int j = 0; j < 8; ++j){
                Sr[j] = fmaf(pc[j], vv, Sr[j]);
                Si[j] = fmaf(ps[j], vv, Si[j]);
            }
            pc[0]=c0.x; pc[1]=c0.y; pc[2]=c0.z; pc[3]=c0.w;
            pc[4]=c1.x; pc[5]=c1.y; pc[6]=c1.z; pc[7]=c1.w;
            ps[0]=s0.x; ps[1]=s0.y; ps[2]=s0.z; ps[3]=s0.w;
            ps[4]=s1.x; ps[5]=s1.y; ps[6]=s1.z; ps[7]=s1.w;
        }
        #pragma unroll
        for (int j = 0; j < 8; ++j){
            size_t o = (size_t)((b * NC_ + c) * P_ + p0 + j) * D_ + d;
            kvSr[o] = Sr[j]; kvSi[o] = Si[j];
        }
    }
}

// ---------------- K_prefix: exclusive prefix over 64 chunks, float4, 8-seg ----
__global__ __launch_bounds__(256) void k_prefix(
    float* __restrict__ posSr, float* __restrict__ posSi,
    float* __restrict__ kvSr, float* __restrict__ kvSi)
{
    __shared__ float4 tot_s[32][8];
    const int colLocal = threadIdx.x >> 3, seg = threadIdx.x & 7;
    const int col = blockIdx.x * 32 + colLocal;
    const int a = col >> 12;
    const int rem = col & 4095;
    const int b = rem >> 11;
    const int pd = (rem & 2047) * 4;
    float* A = (a == 0) ? posSr : (a == 1) ? posSi : (a == 2) ? kvSr : kvSi;
    float* base = A + (size_t)b * NC_ * (P_ * D_) + pd;

    float4 t[8];
    #pragma unroll
    for (int k = 0; k < 8; ++k)
        t[k] = *(const float4*)(base + (size_t)(seg * 8 + k) * (P_ * D_));
    float4 tot = {0.f, 0.f, 0.f, 0.f};
    #pragma unroll
    for (int k = 0; k < 8; ++k){
        tot.x += t[k].x; tot.y += t[k].y; tot.z += t[k].z; tot.w += t[k].w;
    }
    tot_s[colLocal][seg] = tot;
    __syncthreads();
    float4 run = {0.f, 0.f, 0.f, 0.f};
    #pragma unroll
    for (int s = 0; s < 7; ++s){
        if (s < seg){
            float4 v = tot_s[colLocal][s];
            run.x += v.x; run.y += v.y; run.z += v.z; run.w += v.w;
        }
    }
    #pragma unroll
    for (int k = 0; k < 8; ++k){
        float4 cur = t[k];
        *(float4*)(base + (size_t)(seg * 8 + k) * (P_ * D_)) = run;
        run.x += cur.x; run.y += cur.y; run.z += cur.z; run.w += cur.w;
    }
}

// ---------------- K_retrieve: P split 4-way across lanes, shfl reduce --------
__global__ __launch_bounds__(256) void k_retrieve(
    const float* __restrict__ cpos, const float* __restrict__ spos,
    const float* __restrict__ ck, const float* __restrict__ sk,
    const unsigned short* __restrict__ pvb, const unsigned short* __restrict__ kvvb,
    const float* __restrict__ rnorm,
    const float* __restrict__ posSr, const float* __restrict__ posSi,
    const float* __restrict__ kvSr, const float* __restrict__ kvSi,
    unsigned short* __restrict__ posretb, unsigned short* __restrict__ kvretb)
{
    const int z = blockIdx.z;
    const int c = blockIdx.x, b = blockIdx.y;
    const int type = z >> 2, dquad = z & 3;
    const int lane = threadIdx.x & 63, wv = threadIdx.x >> 6;
    const int pg = lane >> 4, dl = lane & 15;
    const int d = dquad * 64 + wv * 16 + dl;
    const int p0 = pg * 8;

    float Sr[8], Si[8];

    if (type == 0){
        #pragma unroll
        for (int j = 0; j < 8; ++j){
            size_t o = (size_t)((b * NC_ + c) * P_ + p0 + j) * D_ + d;
            Sr[j] = posSr[o]; Si[j] = posSi[o];
        }
        for (int l = 0; l < CL_; ++l){
            int row = c * CL_ + l;
            float v = bf2f(pvb[(size_t)(b * L_ + row) * D_ + d]);
            float4 c0 = *(const float4*)(cpos + row * P_ + p0);
            float4 c1 = *(const float4*)(cpos + row * P_ + p0 + 4);
            float4 s0 = *(const float4*)(spos + row * P_ + p0);
            float4 s1 = *(const float4*)(spos + row * P_ + p0 + 4);
            float r0 = 0.f, r1 = 0.f, r2 = 0.f, r3 = 0.f;
            Sr[0] = fmaf(c0.x, v, Sr[0]); r0 = fmaf(c0.x, Sr[0], r0);
            Si[0] = fmaf(s0.x, v, Si[0]); r1 = fmaf(s0.x, Si[0], r1);
            Sr[1] = fmaf(c0.y, v, Sr[1]); r2 = fmaf(c0.y, Sr[1], r2);
            Si[1] = fmaf(s0.y, v, Si[1]); r3 = fmaf(s0.y, Si[1], r3);
            Sr[2] = fmaf(c0.z, v, Sr[2]); r0 = fmaf(c0.z, Sr[2], r0);
            Si[2] = fmaf(s0.z, v, Si[2]); r1 = fmaf(s0.z, Si[2], r1);
            Sr[3] = fmaf(c0.w, v, Sr[3]); r2 = fmaf(c0.w, Sr[3], r2);
            Si[3] = fmaf(s0.w, v, Si[3]); r3 = fmaf(s0.w, Si[3], r3);
            Sr[4] = fmaf(c1.x, v, Sr[4]); r0 = fmaf(c1.x, Sr[4], r0);
            Si[4] = fmaf(s1.x, v, Si[4]); r1 = fmaf(s1.x, Si[4], r1);
            Sr[5] = fmaf(c1.y, v, Sr[5]); r2 = fmaf(c1.y, Sr[5], r2);
            Si[5] = fmaf(s1.y, v, Si[5]); r3 = fmaf(s1.y, Si[5], r3);
            Sr[6] = fmaf(c1.z, v, Sr[6]); r0 = fmaf(c1.z, Sr[6], r0);
            Si[6] = fmaf(s1.z, v, Si[6]); r1 = fmaf(s1.z, Si[6], r1);
            Sr[7] = fmaf(c1.w, v, Sr[7]); r2 = fmaf(c1.w, Sr[7], r2);
            Si[7] = fmaf(s1.w, v, Si[7]); r3 = fmaf(s1.w, Si[7], r3);
            float r = (r0 + r1) + (r2 + r3);
            r += __shfl_xor(r, 16, 64);
            r += __shfl_xor(r, 32, 64);
            if (pg == 0)
                posretb[(size_t)(b * L_ + row) * D_ + d] = f2bf(r * INV_SQRT_P);
        }
    } else {
        #pragma unroll
        for (int j = 0; j < 8; ++j){
            size_t o = (size_t)((b * NC_ + c) * P_ + p0 + j) * D_ + d;
            Sr[j] = kvSr[o]; Si[j] = kvSi[o];
        }
        float pc[8], ps[8];
        int srow = c * CL_ - 1;
        if (srow >= 0){
            float4 c0 = *(const float4*)(ck + ((size_t)b * L_ + srow) * P_ + p0);
            float4 c1 = *(const float4*)(ck + ((size_t)b * L_ + srow) * P_ + p0 + 4);
            float4 s0 = *(const float4*)(sk + ((size_t)b * L_ + srow) * P_ + p0);
            float4 s1 = *(const float4*)(sk + ((size_t)b * L_ + srow) * P_ + p0 + 4);
            pc[0]=c0.x; pc[1]=c0.y; pc[2]=c0.z; pc[3]=c0.w;
            pc[4]=c1.x; pc[5]=c1.y; pc[6]=c1.z; pc[7]=c1.w;
            ps[0]=s0.x; ps[1]=s0.y; ps[2]=s0.z; ps[3]=s0.w;
            ps[4]=s1.x; ps[5]=s1.y; ps[6]=s1.z; ps[7]=s1.w;
        } else {
            #pragma unroll
            for (int j = 0; j < 8; ++j){ pc[j] = 0.f; ps[j] = 0.f; }
        }
        for (int l = 0; l < CL_; ++l){
            int row = c * CL_ + l;
            float vv = bf2f(kvvb[(size_t)(b * L_ + row) * D_ + d]);  // pre-gated
            float rn = rnorm[b * L_ + row];
            float4 c0 = *(const float4*)(ck + ((size_t)b * L_ + row) * P_ + p0);
            float4 c1 = *(const float4*)(ck + ((size_t)b * L_ + row) * P_ + p0 + 4);
            float4 s0 = *(const float4*)(sk + ((size_t)b * L_ + row) * P_ + p0);
            float4 s1 = *(const float4*)(sk + ((size_t)b * L_ + row) * P_ + p0 + 4);
            float qc[8], qs[8];
            qc[0]=c0.x; qc[1]=c0.y; qc[2]=c0.z; qc[3]=c0.w;
            qc[4]=c1.x; qc[5]=c1.y; qc[6]=c1.z; qc[7]=c1.w;
            qs[0]=s0.x; qs[1]=s0.y; qs[2]=s0.z; qs[3]=s0.w;
            qs[4]=s1.x; qs[5]=s1.y; qs[6]=s1.z; qs[7]=s1.w;
            float r0 = 0.f, r1 = 0.f, r2 = 0.f, r3 = 0.f;
            #pragma unroll
            for (int j = 0; j < 8; ++j){
                Sr[j] = fmaf(pc[j], vv, Sr[j]);
                Si[j] = fmaf(ps[j], vv, Si[j]);
                if (j & 1){ r2 = fmaf(qc[j], Sr[j], r2); r3 = fmaf(qs[j], Si[j], r3); }
                else      { r0 = fmaf(qc[j], Sr[j], r0); r1 = fmaf(qs[j], Si[j], r1); }
                pc[j] = qc[j]; ps[j] = qs[j];
            }
            float r = (r0 + r1) + (r2 + r3);
            r += __shfl_xor(r, 16, 64);
            r += __shfl_xor(r, 32, 64);
            if (pg == 0)
                kvretb[(size_t)(b * L_ + row) * D_ + d] = f2bf(r * rn);
        }
    }
}

// ---------------- K9: blend -> LN -> r1 -> r2 -> LN -> out, 16 waves ---------
__global__ __launch_bounds__(1024) void k_final(
    const float* __restrict__ x,
    const unsigned short* __restrict__ posretb, const unsigned short* __restrict__ kvretb,
    const float* __restrict__ blend0, const float* __restrict__ blend1,
    const unsigned short* __restrict__ wq,
    const float* __restrict__ ln_r_g, const float* __restrict__ ln_r_b,
    const float* __restrict__ b_r1, const float* __restrict__ b_r2,
    const float* __restrict__ ln_o_g, const float* __restrict__ ln_o_b,
    const float* __restrict__ b_out,
    float* __restrict__ out)
{
    __shared__ float zbuf[16][257];
    __shared__ __align__(16) unsigned short aA[8][512];
    __shared__ __align__(16) unsigned short aH[16][512];
    __shared__ float red[16][17], red2[16][17];
    __shared__ float mu[16], rs[16];

    const int i = threadIdx.x, lane = i & 63, w = i >> 6;   // w 0..15
    const int b = blockIdx.x >> 7, l0 = (blockIdx.x & 127) * 16;
    const int g = lane >> 4, c = lane & 15;
    const unsigned short* wr1  = wq + 294912;
    const unsigned short* wr2  = wq + 425984;
    const unsigned short* wout = wq + 557056;

    // load bf16 posret/kvret + blend -> zbuf fp32 (threads 0..511)
    if (i < 512){
        int t = i >> 5, c0 = (i & 31) * 8;
        size_t base = (size_t)(b * L_ + l0 + t) * D_ + c0;
        float w0 = blend0[b * L_ + l0 + t], w1 = blend1[b * L_ + l0 + t];
        bf16x8 pp = *(const bf16x8*)(posretb + base);
        bf16x8 kk = *(const bf16x8*)(kvretb + base);
        #pragma unroll
        for (int m = 0; m < 8; ++m)
            zbuf[t][c0 + m] = w0 * bf2f((unsigned short)pp[m])
                            + w1 * bf2f((unsigned short)kk[m]);
    }
    __syncthreads();

    if (i < 256){
        int t = i >> 4, c2 = i & 15;
        float s = 0.f, s2 = 0.f;
        #pragma unroll
        for (int m = 0; m < 16; ++m){ float v = zbuf[t][c2 + 16 * m]; s += v; s2 += v * v; }
        red[t][c2] = s; red2[t][c2] = s2;
    }
    __syncthreads();
    if (i < 16){
        float s = 0.f, s2 = 0.f;
        #pragma unroll
        for (int c2 = 0; c2 < 16; ++c2){ s += red[i][c2]; s2 += red2[i][c2]; }
        float mean = s * (1.0f / 256.0f);
        float var  = s2 * (1.0f / 256.0f) - mean * mean;
        mu[i] = mean; rs[i] = rsqrtf(var + 1e-5f);
    }
    __syncthreads();

    // repack LN1 -> aA (threads 0..511)
    if (i < 512){
        int kt = i >> 6;
        int t2 = lane & 15, kb = kt * 32 + ((lane >> 4) << 3);
        float m_ = mu[t2], r_ = rs[t2];
        bf16x8 v8;
        #pragma unroll
        for (int j = 0; j < 8; ++j){
            int k = kb + j;
            float v = (zbuf[t2][k] - m_) * r_ * ln_r_g[k] + ln_r_b[k];
            v8[j] = (short)f2bf(v);
        }
        *(bf16x8*)&aA[kt][lane * 8] = v8;
    }
    __syncthreads();

    // r1: 32 N-tiles over 16 waves (2 each)
    {
        bf16x8 afr[8];
        #pragma unroll
        for (int kt = 0; kt < 8; ++kt) afr[kt] = *(const bf16x8*)&aA[kt][lane * 8];
        #pragma unroll
        for (int q = 0; q < 2; ++q){
            int nt = w + 16 * q;
            f32x4 acc = {0.f, 0.f, 0.f, 0.f};
            #pragma unroll
            for (int kt = 0; kt < 8; ++kt){
                bf16x8 bf = *(const bf16x8*)(wr1 + (kt * 32 + nt) * 512 + lane * 8);
                acc = __builtin_amdgcn_mfma_f32_16x16x32_bf16(afr[kt], bf, acc, 0, 0, 0);
            }
            float bb = b_r1[nt * 16 + c];
            #pragma unroll
            for (int r = 0; r < 4; ++r){
                float hv = gelu_exact(acc[r] + bb);
                int t = 4 * g + r, hcol = nt * 16 + c;
                int kt2 = hcol >> 5, kk = hcol & 31;
                int lane2 = ((kk >> 3) << 4) + t, j2 = kk & 7;
                aH[kt2][lane2 * 8 + j2] = f2bf(hv);
            }
        }
    }
    __syncthreads();

    // r2: 16 N-tiles over 16 waves (1 each), K=512
    {
        int nt = w;
        f32x4 acc = {0.f, 0.f, 0.f, 0.f};
        #pragma unroll
        for (int kt = 0; kt < 16; ++kt){
            bf16x8 hfr = *(const bf16x8*)&aH[kt][lane * 8];
            bf16x8 bf = *(const bf16x8*)(wr2 + (kt * 16 + nt) * 512 + lane * 8);
            acc = __builtin_amdgcn_mfma_f32_16x16x32_bf16(hfr, bf, acc, 0, 0, 0);
        }
        float bb = b_r2[nt * 16 + c];
        #pragma unroll
        for (int r = 0; r < 4; ++r)
            zbuf[4 * g + r][nt * 16 + c] = acc[r] + bb;
    }
    __syncthreads();

    if (i < 256){
        int t = i >> 4, c2 = i & 15;
        float s = 0.f, s2 = 0.f;
        #pragma unroll
        for (int m = 0; m < 16; ++m){ float v = zbuf[t][c2 + 16 * m]; s += v; s2 += v * v; }
        red[t][c2] = s; red2[t][c2] = s2;
    }
    __syncthreads();
    if (i < 16){
        float s = 0.f, s2 = 0.f;
        #pragma unroll
        for (int c2 = 0; c2 < 16; ++c2){ s += red[i][c2]; s2 += red2[i][c2]; }
        float mean = s * (1.0f / 256.0f);
        float var  = s2 * (1.0f / 256.0f) - mean * mean;
        mu[i] = mean; rs[i] = rsqrtf(var + 1e-5f);
    }
    __syncthreads();

    // repack LN2 -> aA (threads 0..511)
    if (i < 512){
        int kt = i >> 6;
        int t2 = lane & 15, kb = kt * 32 + ((lane >> 4) << 3);
        float m_ = mu[t2], r_ = rs[t2];
        bf16x8 v8;
        #pragma unroll
        for (int j = 0; j < 8; ++j){
            int k = kb + j;
            float v = (zbuf[t2][k] - m_) * r_ * ln_o_g[k] + ln_o_b[k];
            v8[j] = (short)f2bf(v);
        }
        *(bf16x8*)&aA[kt][lane * 8] = v8;
    }
    __syncthreads();

    // out: 16 N-tiles over 16 waves (1 each) + residual
    {
        int nt = w;
        f32x4 acc = {0.f, 0.f, 0.f, 0.f};
        #pragma unroll
        for (int kt = 0; kt < 8; ++kt){
            bf16x8 azr = *(const bf16x8*)&aA[kt][lane * 8];
            bf16x8 bf = *(const bf16x8*)(wout + (kt * 16 + nt) * 512 + lane * 8);
            acc = __builtin_amdgcn_mfma_f32_16x16x32_bf16(azr, bf, acc, 0, 0, 0);
        }
        float bb = b_out[nt * 16 + c];
        #pragma unroll
        for (int r = 0; r < 4; ++r){
            size_t o = (size_t)(b * L_ + l0 + 4 * g + r) * D_ + nt * 16 + c;
            out[o] = x[o] + acc[r] + bb;
        }
    }
}

extern "C" void kernel_launch(void* const* d_in, const int* in_sizes, int n_in,
                              void* d_out, int out_size, void* d_ws, size_t ws_size,
                              hipStream_t stream) {
    const float* x          = (const float*)d_in[0];
    const float* pos_phases = (const float*)d_in[1];
    const float* w_pv       = (const float*)d_in[2];
    const float* b_pv       = (const float*)d_in[3];
    const float* w_key      = (const float*)d_in[4];
    const float* b_key      = (const float*)d_in[5];
    const float* w_kv       = (const float*)d_in[6];
    const float* b_kv       = (const float*)d_in[7];
    const float* w_vg1      = (const float*)d_in[8];
    const float* b_vg1      = (const float*)d_in[9];
    const float* w_vg2      = (const float*)d_in[10];
    const float* b_vg2      = (const float*)d_in[11];
    const float* w_bg1      = (const float*)d_in[12];
    const float* b_bg1      = (const float*)d_in[13];
    const float* w_bg2      = (const float*)d_in[14];
    const float* b_bg2      = (const float*)d_in[15];
    const float* ln_r_g     = (const float*)d_in[16];
    const float* ln_r_b     = (const float*)d_in[17];
    const float* w_r1       = (const float*)d_in[18];
    const float* b_r1       = (const float*)d_in[19];
    const float* w_r2       = (const float*)d_in[20];
    const float* b_r2       = (const float*)d_in[21];
    const float* ln_o_g     = (const float*)d_in[22];
    const float* ln_o_b     = (const float*)d_in[23];
    const float* w_out      = (const float*)d_in[24];
    const float* b_out      = (const float*)d_in[25];
    float* out = (float*)d_out;

    float* ws = (float*)d_ws;
    size_t off = 0;
    float* cpos   = ws + off; off += (size_t)L_ * P_;
    float* spos   = ws + off; off += (size_t)L_ * P_;
    float* ck     = ws + off; off += (size_t)B_ * L_ * P_;
    float* sk     = ws + off; off += (size_t)B_ * L_ * P_;
    float* vg     = ws + off; off += (size_t)B_ * L_;
    float* rnorm  = ws + off; off += (size_t)B_ * L_;
    float* blend0 = ws + off; off += (size_t)B_ * L_;
    float* blend1 = ws + off; off += (size_t)B_ * L_;
    float* posSr  = ws + off; off += (size_t)B_ * NC_ * P_ * D_;
    float* posSi  = ws + off; off += (size_t)B_ * NC_ * P_ * D_;
    float* kvSr   = ws + off; off += (size_t)B_ * NC_ * P_ * D_;
    float* kvSi   = ws + off; off += (size_t)B_ * NC_ * P_ * D_;
    unsigned short* wq      = (unsigned short*)(ws + off); off += 630784 / 2;
    unsigned short* pvb     = (unsigned short*)(ws + off); off += (size_t)B_ * L_ * D_ / 2;
    unsigned short* kvvb    = (unsigned short*)(ws + off); off += (size_t)B_ * L_ * D_ / 2;
    unsigned short* posretb = (unsigned short*)(ws + off); off += (size_t)B_ * L_ * D_ / 2;
    unsigned short* kvretb  = (unsigned short*)(ws + off); off += (size_t)B_ * L_ * D_ / 2;

    k_prep<<<2720, 256, 0, stream>>>(pos_phases,
        w_pv, w_kv, w_vg1, w_bg1, w_r1, w_r2, w_out, w_key,
        wq, cpos, spos);

    k_proj<<<B_ * 128, 512, 0, stream>>>(x, wq,
        b_pv, b_kv, b_vg1, w_vg2, b_vg2, b_bg1, w_bg2, b_bg2, b_key,
        pvb, kvvb, ck, sk, vg, blend0, blend1);

    k_scan1<<<dim3(NC_, B_, 9), 256, 0, stream>>>(cpos, spos, ck, sk, pvb, kvvb, vg,
                                                  posSr, posSi, kvSr, kvSi, rnorm);

    k_prefix<<<512, 256, 0, stream>>>(posSr, posSi, kvSr, kvSi);

    k_retrieve<<<dim3(NC_, B_, 8), 256, 0, stream>>>(cpos, spos, ck, sk, pvb, kvvb,
                                                     rnorm,
                                                     posSr, posSi, kvSr, kvSi,
                                                     posretb, kvretb);

    k_final<<<B_ * 128, 1024, 0, stream>>>(x, posretb, kvretb, blend0, blend1, wq,
        ln_r_g, ln_r_b, b_r1, b_r2, ln_o_g, ln_o_b, b_out, out);
}

// Round 17
// 85.445 us; speedup vs baseline: 1.0649x; 1.0048x over previous
//
#include <hip/hip_runtime.h>
#include <math.h>

#define B_ 2
#define L_ 2048
#define D_ 256
#define P_ 32
#define NC_ 64
#define CL_ 32

#define INV_SQRT_P 0.17677669529663687f   // 1/sqrt(32)
#define PI_F 3.14159265358979323846f

typedef __attribute__((ext_vector_type(8))) short bf16x8;
typedef __attribute__((ext_vector_type(4))) float f32x4;

__device__ __forceinline__ float gelu_exact(float x){
    return 0.5f * x * (1.0f + erff(x * 0.70710678118654752f));
}

__device__ __forceinline__ unsigned short f2bf(float f){
    unsigned int u = __float_as_uint(f);
    u += 0x7FFFu + ((u >> 16) & 1u);     // round-to-nearest-even
    return (unsigned short)(u >> 16);
}

__device__ __forceinline__ float bf2f(unsigned short u){
    return __uint_as_float(((unsigned int)u) << 16);
}

// ---------------- K_prep: weight bf16 repacks + pos sincos ----------
__global__ __launch_bounds__(256) void k_prep(
    const float* __restrict__ pos_phases,
    const float* __restrict__ w_pv, const float* __restrict__ w_kv,
    const float* __restrict__ w_vg1, const float* __restrict__ w_bg1,
    const float* __restrict__ w_r1, const float* __restrict__ w_r2,
    const float* __restrict__ w_out, const float* __restrict__ w_key,
    unsigned short* __restrict__ wq,
    float* __restrict__ cpos, float* __restrict__ spos)
{
    int id = blockIdx.x * 256 + threadIdx.x;   // 0..696319
    if (id < 630784){
        const float* src; int N; int local;
        if (id < 65536)       { src = w_pv;  N = 256; local = id; }
        else if (id < 131072) { src = w_kv;  N = 256; local = id - 65536; }
        else if (id < 262144) { src = w_vg1; N = 256; local = id - 131072; }
        else if (id < 294912) { src = w_bg1; N = 128; local = id - 262144; }
        else if (id < 425984) { src = w_r1;  N = 512; local = id - 294912; }
        else if (id < 557056) { src = w_r2;  N = 256; local = id - 425984; }
        else if (id < 622592) { src = w_out; N = 256; local = id - 557056; }
        else                  { src = w_key; N = 32;  local = id - 622592; }
        int j = local & 7, lane = (local >> 3) & 63, tile = local >> 9;
        int NT = N >> 4;
        int nt = tile % NT, kt = tile / NT;
        int row = kt * 32 + ((lane >> 4) << 3) + j;
        int col = nt * 16 + (lane & 15);
        wq[id] = f2bf(src[(size_t)row * N + col]);
    } else {
        int idx = id - 630784;                 // 0..65535 = L*P
        float s, c;
        sincosf(pos_phases[idx], &s, &c);
        cpos[idx] = c;
        spos[idx] = s;
    }
}

// ---------------- K1: fused projections via MFMA, 16 tokens/block, 8 waves ----
// jb loop kept rolled (#pragma unroll 1) to keep code size within I-cache.
__global__ __launch_bounds__(512) void k_proj(
    const float* __restrict__ x,
    const unsigned short* __restrict__ wq,
    const float* __restrict__ b_pv, const float* __restrict__ b_kv,
    const float* __restrict__ b_vg1,
    const float* __restrict__ w_vg2, const float* __restrict__ b_vg2,
    const float* __restrict__ b_bg1,
    const float* __restrict__ w_bg2, const float* __restrict__ b_bg2,
    const float* __restrict__ b_key,
    unsigned short* __restrict__ pvb, unsigned short* __restrict__ kvvb,
    float* __restrict__ ck, float* __restrict__ sk,
    float* __restrict__ vg, float* __restrict__ blend0, float* __restrict__ blend1)
{
    __shared__ float hbuf[16][257];
    __shared__ float kvbuf[16][257];
    __shared__ float bhbuf[16][129];
    __shared__ float kph[16][33];
    __shared__ float red[16][17], red2[16][17], red3[16][17];
    __shared__ float vgs[16];

    const int i = threadIdx.x;
    const int lane = i & 63, w = i >> 6;
    const int b = blockIdx.x >> 7, lt = blockIdx.x & 127, l0 = lt * 16;
    const int g = lane >> 4, c = lane & 15;

    // pack A fragments (x and shifted-x) directly from x
    bf16x8 xa[8], xs[8];
    {
        int row  = l0 + (lane & 15);
        int rowp = row - 1;
        const float* xr = x + (size_t)(b * L_ + row) * D_ + ((lane >> 4) << 3);
        #pragma unroll
        for (int kt = 0; kt < 8; ++kt){
            float4 a0 = *(const float4*)(xr + kt * 32);
            float4 a1 = *(const float4*)(xr + kt * 32 + 4);
            bf16x8 v;
            v[0] = (short)f2bf(a0.x); v[1] = (short)f2bf(a0.y);
            v[2] = (short)f2bf(a0.z); v[3] = (short)f2bf(a0.w);
            v[4] = (short)f2bf(a1.x); v[5] = (short)f2bf(a1.y);
            v[6] = (short)f2bf(a1.z); v[7] = (short)f2bf(a1.w);
            xa[kt] = v;
        }
        if (rowp >= 0){
            const float* xp = x + (size_t)(b * L_ + rowp) * D_ + ((lane >> 4) << 3);
            #pragma unroll
            for (int kt = 0; kt < 8; ++kt){
                float4 a0 = *(const float4*)(xp + kt * 32);
                float4 a1 = *(const float4*)(xp + kt * 32 + 4);
                bf16x8 v;
                v[0] = (short)f2bf(a0.x); v[1] = (short)f2bf(a0.y);
                v[2] = (short)f2bf(a0.z); v[3] = (short)f2bf(a0.w);
                v[4] = (short)f2bf(a1.x); v[5] = (short)f2bf(a1.y);
                v[6] = (short)f2bf(a1.z); v[7] = (short)f2bf(a1.w);
                xs[kt] = v;
            }
        } else {
            #pragma unroll
            for (int kt = 0; kt < 8; ++kt){
                bf16x8 v;
                #pragma unroll
                for (int j = 0; j < 8; ++j) v[j] = 0;
                xs[kt] = v;
            }
        }
    }

    const unsigned short* wpv  = wq;
    const unsigned short* wkv  = wq + 65536;
    const unsigned short* wvg1 = wq + 131072;
    const unsigned short* wbg1 = wq + 262144;
    const unsigned short* wkey = wq + 622592;

    // 58 tile jobs: [0,2) key, [2,18) pv, [18,34) kv, [34,50) vg1(K=512), [50,58) bg1
    #pragma unroll 1
    for (int jb = w; jb < 58; jb += 8){
        f32x4 acc = {0.f, 0.f, 0.f, 0.f};
        if (jb < 2){
            int nt = jb;
            #pragma unroll
            for (int kt = 0; kt < 8; ++kt){
                bf16x8 bf = *(const bf16x8*)(wkey + (kt * 2 + nt) * 512 + lane * 8);
                acc = __builtin_amdgcn_mfma_f32_16x16x32_bf16(xa[kt], bf, acc, 0, 0, 0);
            }
            float bb = b_key[nt * 16 + c];
            #pragma unroll
            for (int r = 0; r < 4; ++r)
                kph[4 * g + r][nt * 16 + c] = acc[r] + bb;
        } else if (jb < 18){
            int nt = jb - 2;
            #pragma unroll
            for (int kt = 0; kt < 8; ++kt){
                bf16x8 bf = *(const bf16x8*)(wpv + (kt * 16 + nt) * 512 + lane * 8);
                acc = __builtin_amdgcn_mfma_f32_16x16x32_bf16(xa[kt], bf, acc, 0, 0, 0);
            }
            float bb = b_pv[nt * 16 + c];
            #pragma unroll
            for (int r = 0; r < 4; ++r)
                pvb[(size_t)(b * L_ + l0 + 4 * g + r) * D_ + nt * 16 + c] = f2bf(acc[r] + bb);
        } else if (jb < 34){
            int nt = jb - 18;
            #pragma unroll
            for (int kt = 0; kt < 8; ++kt){
                bf16x8 bf = *(const bf16x8*)(wkv + (kt * 16 + nt) * 512 + lane * 8);
                acc = __builtin_amdgcn_mfma_f32_16x16x32_bf16(xa[kt], bf, acc, 0, 0, 0);
            }
            float bb = b_kv[nt * 16 + c];
            #pragma unroll
            for (int r = 0; r < 4; ++r)
                kvbuf[4 * g + r][nt * 16 + c] = acc[r] + bb;
        } else if (jb < 50){
            int nt = jb - 34;
            #pragma unroll
            for (int kt = 0; kt < 8; ++kt){
                bf16x8 bf = *(const bf16x8*)(wvg1 + (kt * 16 + nt) * 512 + lane * 8);
                acc = __builtin_amdgcn_mfma_f32_16x16x32_bf16(xa[kt], bf, acc, 0, 0, 0);
            }
            #pragma unroll
            for (int kt = 8; kt < 16; ++kt){
                bf16x8 bf = *(const bf16x8*)(wvg1 + (kt * 16 + nt) * 512 + lane * 8);
                acc = __builtin_amdgcn_mfma_f32_16x16x32_bf16(xs[kt - 8], bf, acc, 0, 0, 0);
            }
            float bb = b_vg1[nt * 16 + c];
            #pragma unroll
            for (int r = 0; r < 4; ++r)
                hbuf[4 * g + r][nt * 16 + c] = gelu_exact(acc[r] + bb);
        } else {
            int nt = jb - 50;
            #pragma unroll
            for (int kt = 0; kt < 8; ++kt){
                bf16x8 bf = *(const bf16x8*)(wbg1 + (kt * 8 + nt) * 512 + lane * 8);
                acc = __builtin_amdgcn_mfma_f32_16x16x32_bf16(xa[kt], bf, acc, 0, 0, 0);
            }
            float bb = b_bg1[nt * 16 + c];
            #pragma unroll
            for (int r = 0; r < 4; ++r)
                bhbuf[4 * g + r][nt * 16 + c] = gelu_exact(acc[r] + bb);
        }
    }
    __syncthreads();

    // key phases -> phasors (fp32)
    {
        int t = i >> 5, p = i & 31;
        float a = tanhf(kph[t][p]) * PI_F;
        float s, cc;
        sincosf(a, &s, &cc);
        ck[(size_t)(b * L_ + l0 + t) * P_ + p] = cc;
        sk[(size_t)(b * L_ + l0 + t) * P_ + p] = s;
    }

    // vg2 (threads 0..255) and bg2 (threads 256..511) partial reductions
    if (i < 256){
        int t = i >> 4, c2 = i & 15;
        float s = 0.f;
        #pragma unroll
        for (int m = 0; m < 16; ++m){ int dd = c2 + 16 * m; s += hbuf[t][dd] * w_vg2[dd]; }
        red[t][c2] = s;
    } else {
        int ii = i - 256;
        int t = ii >> 4, c2 = ii & 15;
        float s0 = 0.f, s1 = 0.f;
        #pragma unroll
        for (int m = 0; m < 8; ++m){
            int jj = c2 + 16 * m;
            float v = bhbuf[t][jj];
            s0 += v * w_bg2[jj * 2 + 0];
            s1 += v * w_bg2[jj * 2 + 1];
        }
        red2[t][c2] = s0; red3[t][c2] = s1;
    }
    __syncthreads();
    if (i < 16){
        float s = 0.f;
        #pragma unroll
        for (int c2 = 0; c2 < 16; ++c2) s += red[i][c2];
        s += b_vg2[0];
        float gv = 1.0f / (1.0f + expf(-s));
        vg[b * L_ + l0 + i] = gv;
        vgs[i] = gv;
    } else if (i < 32){
        int t = i - 16;
        float s0 = 0.f, s1 = 0.f;
        #pragma unroll
        for (int c2 = 0; c2 < 16; ++c2){ s0 += red2[t][c2]; s1 += red3[t][c2]; }
        s0 += b_bg2[0]; s1 += b_bg2[1];
        float mx = fmaxf(s0, s1);
        float e0 = expf(s0 - mx), e1 = expf(s1 - mx);
        float inv = 1.0f / (e0 + e1);
        blend0[b * L_ + l0 + t] = e0 * inv;
        blend1[b * L_ + l0 + t] = e1 * inv;
    }
    __syncthreads();

    // gated kvv store (bf16, coalesced across d): thread = (tg, d)
    {
        int d = i & 255, tg = i >> 8;   // tg 0..1, 8 tokens each
        #pragma unroll
        for (int m = 0; m < 8; ++m){
            int tok = tg * 8 + m;
            kvvb[(size_t)(b * L_ + l0 + tok) * D_ + d] = f2bf(kvbuf[tok][d] * vgs[tok]);
        }
    }
}

// ---------------- K_scan1: chunk sums (NC=64, CL=32) + gatecum (z=8) ----------
__global__ __launch_bounds__(256) void k_scan1(
    const float* __restrict__ cpos, const float* __restrict__ spos,
    const float* __restrict__ ck, const float* __restrict__ sk,
    const unsigned short* __restrict__ pvb, const unsigned short* __restrict__ kvvb,
    const float* __restrict__ vg,
    float* __restrict__ posSr, float* __restrict__ posSi,
    float* __restrict__ kvSr, float* __restrict__ kvSi,
    float* __restrict__ rnorm)
{
    const int z = blockIdx.z;
    const int c = blockIdx.x, b = blockIdx.y;
    const int i = threadIdx.x;
    if (z == 8){
        if (c != 0) return;
        float loc[8];
        float run = 0.f;
        #pragma unroll
        for (int m = 0; m < 8; ++m){ run += vg[b * L_ + i * 8 + m]; loc[m] = run; }
        __shared__ float part[256];
        part[i] = run;
        __syncthreads();
        for (int off = 1; off < 256; off <<= 1){
            float t = (i >= off) ? part[i - off] : 0.0f;
            __syncthreads();
            part[i] += t;
            __syncthreads();
        }
        float excl = part[i] - run;
        #pragma unroll
        for (int m = 0; m < 8; ++m){
            float gc = fmaxf(excl + loc[m], 1.0f);
            rnorm[b * L_ + i * 8 + m] = rsqrtf(gc) * INV_SQRT_P;
        }
        return;
    }
    const int type = z >> 2, pg = z & 3;
    const int d = i;
    const int p0 = pg * 8;
    float Sr[8], Si[8];
    #pragma unroll
    for (int j = 0; j < 8; ++j){ Sr[j] = 0.f; Si[j] = 0.f; }

    if (type == 0){
        for (int l = 0; l < CL_; ++l){
            int row = c * CL_ + l;
            float v = bf2f(pvb[(size_t)(b * L_ + row) * D_ + d]);
            float4 c0 = *(const float4*)(cpos + row * P_ + p0);
            float4 c1 = *(const float4*)(cpos + row * P_ + p0 + 4);
            float4 s0 = *(const float4*)(spos + row * P_ + p0);
            float4 s1 = *(const float4*)(spos + row * P_ + p0 + 4);
            Sr[0] = fmaf(c0.x, v, Sr[0]); Si[0] = fmaf(s0.x, v, Si[0]);
            Sr[1] = fmaf(c0.y, v, Sr[1]); Si[1] = fmaf(s0.y, v, Si[1]);
            Sr[2] = fmaf(c0.z, v, Sr[2]); Si[2] = fmaf(s0.z, v, Si[2]);
            Sr[3] = fmaf(c0.w, v, Sr[3]); Si[3] = fmaf(s0.w, v, Si[3]);
            Sr[4] = fmaf(c1.x, v, Sr[4]); Si[4] = fmaf(s1.x, v, Si[4]);
            Sr[5] = fmaf(c1.y, v, Sr[5]); Si[5] = fmaf(s1.y, v, Si[5]);
            Sr[6] = fmaf(c1.z, v, Sr[6]); Si[6] = fmaf(s1.z, v, Si[6]);
            Sr[7] = fmaf(c1.w, v, Sr[7]); Si[7] = fmaf(s1.w, v, Si[7]);
        }
        #pragma unroll
        for (int j = 0; j < 8; ++j){
            size_t o = (size_t)((b * NC_ + c) * P_ + p0 + j) * D_ + d;
            posSr[o] = Sr[j]; posSi[o] = Si[j];
        }
    } else {
        float pc[8], ps[8];
        int srow = c * CL_ - 1;
        if (srow >= 0){
            float4 c0 = *(const float4*)(ck + ((size_t)b * L_ + srow) * P_ + p0);
            float4 c1 = *(const float4*)(ck + ((size_t)b * L_ + srow) * P_ + p0 + 4);
            float4 s0 = *(const float4*)(sk + ((size_t)b * L_ + srow) * P_ + p0);
            float4 s1 = *(const float4*)(sk + ((size_t)b * L_ + srow) * P_ + p0 + 4);
            pc[0]=c0.x; pc[1]=c0.y; pc[2]=c0.z; pc[3]=c0.w;
            pc[4]=c1.x; pc[5]=c1.y; pc[6]=c1.z; pc[7]=c1.w;
            ps[0]=s0.x; ps[1]=s0.y; ps[2]=s0.z; ps[3]=s0.w;
            ps[4]=s1.x; ps[5]=s1.y; ps[6]=s1.z; ps[7]=s1.w;
        } else {
            #pragma unroll
            for (int j = 0; j < 8; ++j){ pc[j] = 0.f; ps[j] = 0.f; }
        }
        for (int l = 0; l < CL_; ++l){
            int row = c * CL_ + l;
            float vv = bf2f(kvvb[(size_t)(b * L_ + row) * D_ + d]);  // pre-gated
            float4 c0 = *(const float4*)(ck + ((size_t)b * L_ + row) * P_ + p0);
            float4 c1 = *(const float4*)(ck + ((size_t)b * L_ + row) * P_ + p0 + 4);
            float4 s0 = *(const float4*)(sk + ((size_t)b * L_ + row) * P_ + p0);
            float4 s1 = *(const float4*)(sk + ((size_t)b * L_ + row) * P_ + p0 + 4);
            #pragma unroll
            for (int j = 0; j < 8; ++j){
                Sr[j] = fmaf(pc[j], vv, Sr[j]);
                Si[j] = fmaf(ps[j], vv, Si[j]);
            }
            pc[0]=c0.x; pc[1]=c0.y; pc[2]=c0.z; pc[3]=c0.w;
            pc[4]=c1.x; pc[5]=c1.y; pc[6]=c1.z; pc[7]=c1.w;
            ps[0]=s0.x; ps[1]=s0.y; ps[2]=s0.z; ps[3]=s0.w;
            ps[4]=s1.x; ps[5]=s1.y; ps[6]=s1.z; ps[7]=s1.w;
        }
        #pragma unroll
        for (int j = 0; j < 8; ++j){
            size_t o = (size_t)((b * NC_ + c) * P_ + p0 + j) * D_ + d;
            kvSr[o] = Sr[j]; kvSi[o] = Si[j];
        }
    }
}

// ---------------- K_prefix: exclusive prefix over 64 chunks, float4, 8-seg ----
__global__ __launch_bounds__(256) void k_prefix(
    float* __restrict__ posSr, float* __restrict__ posSi,
    float* __restrict__ kvSr, float* __restrict__ kvSi)
{
    __shared__ float4 tot_s[32][8];
    const int colLocal = threadIdx.x >> 3, seg = threadIdx.x & 7;
    const int col = blockIdx.x * 32 + colLocal;
    const int a = col >> 12;
    const int rem = col & 4095;
    const int b = rem >> 11;
    const int pd = (rem & 2047) * 4;
    float* A = (a == 0) ? posSr : (a == 1) ? posSi : (a == 2) ? kvSr : kvSi;
    float* base = A + (size_t)b * NC_ * (P_ * D_) + pd;

    float4 t[8];
    #pragma unroll
    for (int k = 0; k < 8; ++k)
        t[k] = *(const float4*)(base + (size_t)(seg * 8 + k) * (P_ * D_));
    float4 tot = {0.f, 0.f, 0.f, 0.f};
    #pragma unroll
    for (int k = 0; k < 8; ++k){
        tot.x += t[k].x; tot.y += t[k].y; tot.z += t[k].z; tot.w += t[k].w;
    }
    tot_s[colLocal][seg] = tot;
    __syncthreads();
    float4 run = {0.f, 0.f, 0.f, 0.f};
    #pragma unroll
    for (int s = 0; s < 7; ++s){
        if (s < seg){
            float4 v = tot_s[colLocal][s];
            run.x += v.x; run.y += v.y; run.z += v.z; run.w += v.w;
        }
    }
    #pragma unroll
    for (int k = 0; k < 8; ++k){
        float4 cur = t[k];
        *(float4*)(base + (size_t)(seg * 8 + k) * (P_ * D_)) = run;
        run.x += cur.x; run.y += cur.y; run.z += cur.z; run.w += cur.w;
    }
}

// ---------------- K_retrieve: P split 4-way across lanes, shfl reduce --------
__global__ __launch_bounds__(256) void k_retrieve(
    const float* __restrict__ cpos, const float* __restrict__ spos,
    const float* __restrict__ ck, const float* __restrict__ sk,
    const unsigned short* __restrict__ pvb, const unsigned short* __restrict__ kvvb,
    const float* __restrict__ rnorm,
    const float* __restrict__ posSr, const float* __restrict__ posSi,
    const float* __restrict__ kvSr, const float* __restrict__ kvSi,
    unsigned short* __restrict__ posretb, unsigned short* __restrict__ kvretb)
{
    const int z = blockIdx.z;
    const int c = blockIdx.x, b = blockIdx.y;
    const int type = z >> 2, dquad = z & 3;
    const int lane = threadIdx.x & 63, wv = threadIdx.x >> 6;
    const int pg = lane >> 4, dl = lane & 15;
    const int d = dquad * 64 + wv * 16 + dl;
    const int p0 = pg * 8;

    float Sr[8], Si[8];

    if (type == 0){
        #pragma unroll
        for (int j = 0; j < 8; ++j){
            size_t o = (size_t)((b * NC_ + c) * P_ + p0 + j) * D_ + d;
            Sr[j] = posSr[o]; Si[j] = posSi[o];
        }
        for (int l = 0; l < CL_; ++l){
            int row = c * CL_ + l;
            float v = bf2f(pvb[(size_t)(b * L_ + row) * D_ + d]);
            float4 c0 = *(const float4*)(cpos + row * P_ + p0);
            float4 c1 = *(const float4*)(cpos + row * P_ + p0 + 4);
            float4 s0 = *(const float4*)(spos + row * P_ + p0);
            float4 s1 = *(const float4*)(spos + row * P_ + p0 + 4);
            float r0 = 0.f, r1 = 0.f, r2 = 0.f, r3 = 0.f;
            Sr[0] = fmaf(c0.x, v, Sr[0]); r0 = fmaf(c0.x, Sr[0], r0);
            Si[0] = fmaf(s0.x, v, Si[0]); r1 = fmaf(s0.x, Si[0], r1);
            Sr[1] = fmaf(c0.y, v, Sr[1]); r2 = fmaf(c0.y, Sr[1], r2);
            Si[1] = fmaf(s0.y, v, Si[1]); r3 = fmaf(s0.y, Si[1], r3);
            Sr[2] = fmaf(c0.z, v, Sr[2]); r0 = fmaf(c0.z, Sr[2], r0);
            Si[2] = fmaf(s0.z, v, Si[2]); r1 = fmaf(s0.z, Si[2], r1);
            Sr[3] = fmaf(c0.w, v, Sr[3]); r2 = fmaf(c0.w, Sr[3], r2);
            Si[3] = fmaf(s0.w, v, Si[3]); r3 = fmaf(s0.w, Si[3], r3);
            Sr[4] = fmaf(c1.x, v, Sr[4]); r0 = fmaf(c1.x, Sr[4], r0);
            Si[4] = fmaf(s1.x, v, Si[4]); r1 = fmaf(s1.x, Si[4], r1);
            Sr[5] = fmaf(c1.y, v, Sr[5]); r2 = fmaf(c1.y, Sr[5], r2);
            Si[5] = fmaf(s1.y, v, Si[5]); r3 = fmaf(s1.y, Si[5], r3);
            Sr[6] = fmaf(c1.z, v, Sr[6]); r0 = fmaf(c1.z, Sr[6], r0);
            Si[6] = fmaf(s1.z, v, Si[6]); r1 = fmaf(s1.z, Si[6], r1);
            Sr[7] = fmaf(c1.w, v, Sr[7]); r2 = fmaf(c1.w, Sr[7], r2);
            Si[7] = fmaf(s1.w, v, Si[7]); r3 = fmaf(s1.w, Si[7], r3);
            float r = (r0 + r1) + (r2 + r3);
            r += __shfl_xor(r, 16, 64);
            r += __shfl_xor(r, 32, 64);
            if (pg == 0)
                posretb[(size_t)(b * L_ + row) * D_ + d] = f2bf(r * INV_SQRT_P);
        }
    } else {
        #pragma unroll
        for (int j = 0; j < 8; ++j){
            size_t o = (size_t)((b * NC_ + c) * P_ + p0 + j) * D_ + d;
            Sr[j] = kvSr[o]; Si[j] = kvSi[o];
        }
        float pc[8], ps[8];
        int srow = c * CL_ - 1;
        if (srow >= 0){
            float4 c0 = *(const float4*)(ck + ((size_t)b * L_ + srow) * P_ + p0);
            float4 c1 = *(const float4*)(ck + ((size_t)b * L_ + srow) * P_ + p0 + 4);
            float4 s0 = *(const float4*)(sk + ((size_t)b * L_ + srow) * P_ + p0);
            float4 s1 = *(const float4*)(sk + ((size_t)b * L_ + srow) * P_ + p0 + 4);
            pc[0]=c0.x; pc[1]=c0.y; pc[2]=c0.z; pc[3]=c0.w;
            pc[4]=c1.x; pc[5]=c1.y; pc[6]=c1.z; pc[7]=c1.w;
            ps[0]=s0.x; ps[1]=s0.y; ps[2]=s0.z; ps[3]=s0.w;
            ps[4]=s1.x; ps[5]=s1.y; ps[6]=s1.z; ps[7]=s1.w;
        } else {
            #pragma unroll
            for (int j = 0; j < 8; ++j){ pc[j] = 0.f; ps[j] = 0.f; }
        }
        for (int l = 0; l < CL_; ++l){
            int row = c * CL_ + l;
            float vv = bf2f(kvvb[(size_t)(b * L_ + row) * D_ + d]);  // pre-gated
            float rn = rnorm[b * L_ + row];
            float4 c0 = *(const float4*)(ck + ((size_t)b * L_ + row) * P_ + p0);
            float4 c1 = *(const float4*)(ck + ((size_t)b * L_ + row) * P_ + p0 + 4);
            float4 s0 = *(const float4*)(sk + ((size_t)b * L_ + row) * P_ + p0);
            float4 s1 = *(const float4*)(sk + ((size_t)b * L_ + row) * P_ + p0 + 4);
            float qc[8], qs[8];
            qc[0]=c0.x; qc[1]=c0.y; qc[2]=c0.z; qc[3]=c0.w;
            qc[4]=c1.x; qc[5]=c1.y; qc[6]=c1.z; qc[7]=c1.w;
            qs[0]=s0.x; qs[1]=s0.y; qs[2]=s0.z; qs[3]=s0.w;
            qs[4]=s1.x; qs[5]=s1.y; qs[6]=s1.z; qs[7]=s1.w;
            float r0 = 0.f, r1 = 0.f, r2 = 0.f, r3 = 0.f;
            #pragma unroll
            for (int j = 0; j < 8; ++j){
                Sr[j] = fmaf(pc[j], vv, Sr[j]);
                Si[j] = fmaf(ps[j], vv, Si[j]);
                if (j & 1){ r2 = fmaf(qc[j], Sr[j], r2); r3 = fmaf(qs[j], Si[j], r3); }
                else      { r0 = fmaf(qc[j], Sr[j], r0); r1 = fmaf(qs[j], Si[j], r1); }
                pc[j] = qc[j]; ps[j] = qs[j];
            }
            float r = (r0 + r1) + (r2 + r3);
            r += __shfl_xor(r, 16, 64);
            r += __shfl_xor(r, 32, 64);
            if (pg == 0)
                kvretb[(size_t)(b * L_ + row) * D_ + d] = f2bf(r * rn);
        }
    }
}

// ---------------- K9: blend -> LN -> r1 -> r2 -> LN -> out, 16 waves ---------
__global__ __launch_bounds__(1024) void k_final(
    const float* __restrict__ x,
    const unsigned short* __restrict__ posretb, const unsigned short* __restrict__ kvretb,
    const float* __restrict__ blend0, const float* __restrict__ blend1,
    const unsigned short* __restrict__ wq,
    const float* __restrict__ ln_r_g, const float* __restrict__ ln_r_b,
    const float* __restrict__ b_r1, const float* __restrict__ b_r2,
    const float* __restrict__ ln_o_g, const float* __restrict__ ln_o_b,
    const float* __restrict__ b_out,
    float* __restrict__ out)
{
    __shared__ float zbuf[16][257];
    __shared__ __align__(16) unsigned short aA[8][512];
    __shared__ __align__(16) unsigned short aH[16][512];
    __shared__ float red[16][17], red2[16][17];
    __shared__ float mu[16], rs[16];

    const int i = threadIdx.x, lane = i & 63, w = i >> 6;   // w 0..15
    const int b = blockIdx.x >> 7, l0 = (blockIdx.x & 127) * 16;
    const int g = lane >> 4, c = lane & 15;
    const unsigned short* wr1  = wq + 294912;
    const unsigned short* wr2  = wq + 425984;
    const unsigned short* wout = wq + 557056;

    // load bf16 posret/kvret + blend -> zbuf fp32 (threads 0..511)
    if (i < 512){
        int t = i >> 5, c0 = (i & 31) * 8;
        size_t base = (size_t)(b * L_ + l0 + t) * D_ + c0;
        float w0 = blend0[b * L_ + l0 + t], w1 = blend1[b * L_ + l0 + t];
        bf16x8 pp = *(const bf16x8*)(posretb + base);
        bf16x8 kk = *(const bf16x8*)(kvretb + base);
        #pragma unroll
        for (int m = 0; m < 8; ++m)
            zbuf[t][c0 + m] = w0 * bf2f((unsigned short)pp[m])
                            + w1 * bf2f((unsigned short)kk[m]);
    }
    __syncthreads();

    if (i < 256){
        int t = i >> 4, c2 = i & 15;
        float s = 0.f, s2 = 0.f;
        #pragma unroll
        for (int m = 0; m < 16; ++m){ float v = zbuf[t][c2 + 16 * m]; s += v; s2 += v * v; }
        red[t][c2] = s; red2[t][c2] = s2;
    }
    __syncthreads();
    if (i < 16){
        float s = 0.f, s2 = 0.f;
        #pragma unroll
        for (int c2 = 0; c2 < 16; ++c2){ s += red[i][c2]; s2 += red2[i][c2]; }
        float mean = s * (1.0f / 256.0f);
        float var  = s2 * (1.0f / 256.0f) - mean * mean;
        mu[i] = mean; rs[i] = rsqrtf(var + 1e-5f);
    }
    __syncthreads();

    // repack LN1 -> aA (threads 0..511)
    if (i < 512){
        int kt = i >> 6;
        int t2 = lane & 15, kb = kt * 32 + ((lane >> 4) << 3);
        float m_ = mu[t2], r_ = rs[t2];
        bf16x8 v8;
        #pragma unroll
        for (int j = 0; j < 8; ++j){
            int k = kb + j;
            float v = (zbuf[t2][k] - m_) * r_ * ln_r_g[k] + ln_r_b[k];
            v8[j] = (short)f2bf(v);
        }
        *(bf16x8*)&aA[kt][lane * 8] = v8;
    }
    __syncthreads();

    // r1: 32 N-tiles over 16 waves (2 each)
    {
        bf16x8 afr[8];
        #pragma unroll
        for (int kt = 0; kt < 8; ++kt) afr[kt] = *(const bf16x8*)&aA[kt][lane * 8];
        #pragma unroll
        for (int q = 0; q < 2; ++q){
            int nt = w + 16 * q;
            f32x4 acc = {0.f, 0.f, 0.f, 0.f};
            #pragma unroll
            for (int kt = 0; kt < 8; ++kt){
                bf16x8 bf = *(const bf16x8*)(wr1 + (kt * 32 + nt) * 512 + lane * 8);
                acc = __builtin_amdgcn_mfma_f32_16x16x32_bf16(afr[kt], bf, acc, 0, 0, 0);
            }
            float bb = b_r1[nt * 16 + c];
            #pragma unroll
            for (int r = 0; r < 4; ++r){
                float hv = gelu_exact(acc[r] + bb);
                int t = 4 * g + r, hcol = nt * 16 + c;
                int kt2 = hcol >> 5, kk = hcol & 31;
                int lane2 = ((kk >> 3) << 4) + t, j2 = kk & 7;
                aH[kt2][lane2 * 8 + j2] = f2bf(hv);
            }
        }
    }
    __syncthreads();

    // r2: 16 N-tiles over 16 waves (1 each), K=512
    {
        int nt = w;
        f32x4 acc = {0.f, 0.f, 0.f, 0.f};
        #pragma unroll
        for (int kt = 0; kt < 16; ++kt){
            bf16x8 hfr = *(const bf16x8*)&aH[kt][lane * 8];
            bf16x8 bf = *(const bf16x8*)(wr2 + (kt * 16 + nt) * 512 + lane * 8);
            acc = __builtin_amdgcn_mfma_f32_16x16x32_bf16(hfr, bf, acc, 0, 0, 0);
        }
        float bb = b_r2[nt * 16 + c];
        #pragma unroll
        for (int r = 0; r < 4; ++r)
            zbuf[4 * g + r][nt * 16 + c] = acc[r] + bb;
    }
    __syncthreads();

    if (i < 256){
        int t = i >> 4, c2 = i & 15;
        float s = 0.f, s2 = 0.f;
        #pragma unroll
        for (int m = 0; m < 16; ++m){ float v = zbuf[t][c2 + 16 * m]; s += v; s2 += v * v; }
        red[t][c2] = s; red2[t][c2] = s2;
    }
    __syncthreads();
    if (i < 16){
        float s = 0.f, s2 = 0.f;
        #pragma unroll
        for (int c2 = 0; c2 < 16; ++c2){ s += red[i][c2]; s2 += red2[i][c2]; }
        float mean = s * (1.0f / 256.0f);
        float var  = s2 * (1.0f / 256.0f) - mean * mean;
        mu[i] = mean; rs[i] = rsqrtf(var + 1e-5f);
    }
    __syncthreads();

    // repack LN2 -> aA (threads 0..511)
    if (i < 512){
        int kt = i >> 6;
        int t2 = lane & 15, kb = kt * 32 + ((lane >> 4) << 3);
        float m_ = mu[t2], r_ = rs[t2];
        bf16x8 v8;
        #pragma unroll
        for (int j = 0; j < 8; ++j){
            int k = kb + j;
            float v = (zbuf[t2][k] - m_) * r_ * ln_o_g[k] + ln_o_b[k];
            v8[j] = (short)f2bf(v);
        }
        *(bf16x8*)&aA[kt][lane * 8] = v8;
    }
    __syncthreads();

    // out: 16 N-tiles over 16 waves (1 each) + residual
    {
        int nt = w;
        f32x4 acc = {0.f, 0.f, 0.f, 0.f};
        #pragma unroll
        for (int kt = 0; kt < 8; ++kt){
            bf16x8 azr = *(const bf16x8*)&aA[kt][lane * 8];
            bf16x8 bf = *(const bf16x8*)(wout + (kt * 16 + nt) * 512 + lane * 8);
            acc = __builtin_amdgcn_mfma_f32_16x16x32_bf16(azr, bf, acc, 0, 0, 0);
        }
        float bb = b_out[nt * 16 + c];
        #pragma unroll
        for (int r = 0; r < 4; ++r){
            size_t o = (size_t)(b * L_ + l0 + 4 * g + r) * D_ + nt * 16 + c;
            out[o] = x[o] + acc[r] + bb;
        }
    }
}

extern "C" void kernel_launch(void* const* d_in, const int* in_sizes, int n_in,
                              void* d_out, int out_size, void* d_ws, size_t ws_size,
                              hipStream_t stream) {
    const float* x          = (const float*)d_in[0];
    const float* pos_phases = (const float*)d_in[1];
    const float* w_pv       = (const float*)d_in[2];
    const float* b_pv       = (const float*)d_in[3];
    const float* w_key      = (const float*)d_in[4];
    const float* b_key      = (const float*)d_in[5];
    const float* w_kv       = (const float*)d_in[6];
    const float* b_kv       = (const float*)d_in[7];
    const float* w_vg1      = (const float*)d_in[8];
    const float* b_vg1      = (const float*)d_in[9];
    const float* w_vg2      = (const float*)d_in[10];
    const float* b_vg2      = (const float*)d_in[11];
    const float* w_bg1      = (const float*)d_in[12];
    const float* b_bg1      = (const float*)d_in[13];
    const float* w_bg2      = (const float*)d_in[14];
    const float* b_bg2      = (const float*)d_in[15];
    const float* ln_r_g     = (const float*)d_in[16];
    const float* ln_r_b     = (const float*)d_in[17];
    const float* w_r1       = (const float*)d_in[18];
    const float* b_r1       = (const float*)d_in[19];
    const float* w_r2       = (const float*)d_in[20];
    const float* b_r2       = (const float*)d_in[21];
    const float* ln_o_g     = (const float*)d_in[22];
    const float* ln_o_b     = (const float*)d_in[23];
    const float* w_out      = (const float*)d_in[24];
    const float* b_out      = (const float*)d_in[25];
    float* out = (float*)d_out;

    float* ws = (float*)d_ws;
    size_t off = 0;
    float* cpos   = ws + off; off += (size_t)L_ * P_;
    float* spos   = ws + off; off += (size_t)L_ * P_;
    float* ck     = ws + off; off += (size_t)B_ * L_ * P_;
    float* sk     = ws + off; off += (size_t)B_ * L_ * P_;
    float* vg     = ws + off; off += (size_t)B_ * L_;
    float* rnorm  = ws + off; off += (size_t)B_ * L_;
    float* blend0 = ws + off; off += (size_t)B_ * L_;
    float* blend1 = ws + off; off += (size_t)B_ * L_;
    float* posSr  = ws + off; off += (size_t)B_ * NC_ * P_ * D_;
    float* posSi  = ws + off; off += (size_t)B_ * NC_ * P_ * D_;
    float* kvSr   = ws + off; off += (size_t)B_ * NC_ * P_ * D_;
    float* kvSi   = ws + off; off += (size_t)B_ * NC_ * P_ * D_;
    unsigned short* wq      = (unsigned short*)(ws + off); off += 630784 / 2;
    unsigned short* pvb     = (unsigned short*)(ws + off); off += (size_t)B_ * L_ * D_ / 2;
    unsigned short* kvvb    = (unsigned short*)(ws + off); off += (size_t)B_ * L_ * D_ / 2;
    unsigned short* posretb = (unsigned short*)(ws + off); off += (size_t)B_ * L_ * D_ / 2;
    unsigned short* kvretb  = (unsigned short*)(ws + off); off += (size_t)B_ * L_ * D_ / 2;

    k_prep<<<2720, 256, 0, stream>>>(pos_phases,
        w_pv, w_kv, w_vg1, w_bg1, w_r1, w_r2, w_out, w_key,
        wq, cpos, spos);

    k_proj<<<B_ * 128, 512, 0, stream>>>(x, wq,
        b_pv, b_kv, b_vg1, w_vg2, b_vg2, b_bg1, w_bg2, b_bg2, b_key,
        pvb, kvvb, ck, sk, vg, blend0, blend1);

    k_scan1<<<dim3(NC_, B_, 9), 256, 0, stream>>>(cpos, spos, ck, sk, pvb, kvvb, vg,
                                                  posSr, posSi, kvSr, kvSi, rnorm);

    k_prefix<<<512, 256, 0, stream>>>(posSr, posSi, kvSr, kvSi);

    k_retrieve<<<dim3(NC_, B_, 8), 256, 0, stream>>>(cpos, spos, ck, sk, pvb, kvvb,
                                                     rnorm,
                                                     posSr, posSi, kvSr, kvSi,
                                                     posretb, kvretb);

    k_final<<<B_ * 128, 1024, 0, stream>>>(x, posretb, kvretb, blend0, blend1, wq,
        ln_r_g, ln_r_b, b_r1, b_r2, ln_o_g, ln_o_b, b_out, out);
}